// Round 1
// baseline (1115.286 us; speedup 1.0000x reference)
//
#include <hip/hip_runtime.h>
#include <hip/hip_bf16.h>
#include <cstdint>
#include <cstddef>

// Problem constants (B=4, T=2048, DIM=2048, S=4, DFF=8192)
#define DIM   2048
#define DFF   8192
#define NROWS 8192   // B*T
#define NFOLD 24     // 4 (pre) + 4 (post) + 16 (res)

typedef float f32x4 __attribute__((ext_vector_type(4)));
typedef __bf16 bf16x8 __attribute__((ext_vector_type(8)));

__device__ __forceinline__ float sigmoidf_(float v) { return 1.0f / (1.0f + expf(-v)); }

__device__ __forceinline__ unsigned short f2bf(float v) {
    union { __hip_bfloat16 h; unsigned short u; } cv;
    cv.h = __float2bfloat16(v);
    return cv.u;
}

__device__ __forceinline__ void async_copy16(const void* g, void* l) {
    __builtin_amdgcn_global_load_lds((const __attribute__((address_space(1))) void*)g,
                                     (__attribute__((address_space(3))) void*)l, 16, 0, 0);
}

// ---------------------------------------------------------------------------
// Fold phi weights: Wfold[r][d] = sum_{j<4} src[r][j*DIM + d], r in [0,24)
// rows 0..3 = phi_pre_w, 4..7 = phi_post_w, 8..23 = phi_res_w
// ---------------------------------------------------------------------------
__global__ __launch_bounds__(256) void fold_kernel(const float* __restrict__ pre_w,
                                                   const float* __restrict__ post_w,
                                                   const float* __restrict__ res_w,
                                                   float* __restrict__ Wfold) {
    int idx = blockIdx.x * 256 + threadIdx.x;
    if (idx >= NFOLD * DIM) return;
    int r = idx >> 11;          // /DIM
    int d = idx & (DIM - 1);
    const float* src;
    if (r < 4)      src = pre_w  + (size_t)r * (4 * DIM);
    else if (r < 8) src = post_w + (size_t)(r - 4) * (4 * DIM);
    else            src = res_w  + (size_t)(r - 8) * (4 * DIM);
    Wfold[idx] = src[d] + src[DIM + d] + src[2 * DIM + d] + src[3 * DIM + d];
}

// ---------------------------------------------------------------------------
// Transpose f32 [R][C] -> bf16 [C][R]
// ---------------------------------------------------------------------------
__global__ __launch_bounds__(256) void transpose_to_bf16(const float* __restrict__ in,
                                                         __hip_bfloat16* __restrict__ out,
                                                         int R, int C) {
    __shared__ float tile[32][33];
    int bx = blockIdx.x, by = blockIdx.y;
    int tx = threadIdx.x & 31, ty0 = threadIdx.x >> 5;  // ty0 in [0,8)
#pragma unroll
    for (int i = 0; i < 4; i++) {
        int ty = ty0 + i * 8;
        tile[ty][tx] = in[(size_t)(by * 32 + ty) * C + bx * 32 + tx];
    }
    __syncthreads();
#pragma unroll
    for (int i = 0; i < 4; i++) {
        int ty = ty0 + i * 8;
        out[(size_t)(bx * 32 + ty) * R + by * 32 + tx] = __float2bfloat16(tile[tx][ty]);
    }
}

// ---------------------------------------------------------------------------
// Gating: per row -> g_pre (folded into A = bf16(x*g_pre)), g_post, g_res
// One block (256 threads) per row of 2048 floats.
// ---------------------------------------------------------------------------
__global__ __launch_bounds__(256) void gating_kernel(
    const float* __restrict__ x, const float* __restrict__ Wfold,
    const float* __restrict__ phi_pre_b, const float* __restrict__ phi_post_b,
    const float* __restrict__ phi_res_b,
    const float* __restrict__ alpha_pre, const float* __restrict__ alpha_post,
    const float* __restrict__ alpha_res,
    const float* __restrict__ b_pre, const float* __restrict__ b_post,
    const float* __restrict__ b_res,
    __hip_bfloat16* __restrict__ Abuf,
    float* __restrict__ g_res_arr, float* __restrict__ g_post_arr) {
    const int row = blockIdx.x;
    const int tid = threadIdx.x;
    const int lane = tid & 63, wave = tid >> 6;

    const float4* xr = (const float4*)(x + (size_t)row * DIM);
    float4 xv0 = xr[tid];
    float4 xv1 = xr[tid + 256];

    float p[25];
    p[24] = xv0.x * xv0.x + xv0.y * xv0.y + xv0.z * xv0.z + xv0.w * xv0.w +
            xv1.x * xv1.x + xv1.y * xv1.y + xv1.z * xv1.z + xv1.w * xv1.w;
#pragma unroll
    for (int r = 0; r < NFOLD; r++) {
        const float4* w = (const float4*)(Wfold + (size_t)r * DIM);
        float4 w0 = w[tid], w1 = w[tid + 256];
        p[r] = xv0.x * w0.x + xv0.y * w0.y + xv0.z * w0.z + xv0.w * w0.w +
               xv1.x * w1.x + xv1.y * w1.y + xv1.z * w1.z + xv1.w * w1.w;
    }

    __shared__ float red[4][25];
    __shared__ float fin[25];
    __shared__ float bcast;
#pragma unroll
    for (int r = 0; r < 25; r++) {
        float v = p[r];
#pragma unroll
        for (int off = 32; off; off >>= 1) v += __shfl_down(v, off, 64);
        if (lane == 0) red[wave][r] = v;
    }
    __syncthreads();
    if (tid < 25) fin[tid] = red[0][tid] + red[1][tid] + red[2][tid] + red[3][tid];
    __syncthreads();
    if (tid == 0) {
        float rms = rsqrtf(fin[24] / (float)DIM + 1.1920928955078125e-07f);
        float ap = alpha_pre[0], aq = alpha_post[0], ar = alpha_res[0];
        float gpre = 0.f, gpost = 0.f;
#pragma unroll
        for (int s = 0; s < 4; s++) {
            gpre  += sigmoidf_(ap * (rms * fin[s]     + phi_pre_b[s])  + b_pre[s]);
            gpost += 2.0f * sigmoidf_(aq * (rms * fin[4 + s] + phi_post_b[s]) + b_post[s]);
        }
        float Mm[4][4];
#pragma unroll
        for (int i = 0; i < 4; i++)
#pragma unroll
            for (int j = 0; j < 4; j++) {
                int k = i * 4 + j;
                Mm[i][j] = expf(ar * (rms * fin[8 + k] + phi_res_b[k]) + b_res[k]);
            }
        for (int it = 0; it < 10; ++it) {
            for (int i = 0; i < 4; i++) {
                float rs = Mm[i][0] + Mm[i][1] + Mm[i][2] + Mm[i][3];
                for (int j = 0; j < 4; j++) Mm[i][j] /= rs;
            }
            for (int j = 0; j < 4; j++) {
                float cs = Mm[0][j] + Mm[1][j] + Mm[2][j] + Mm[3][j];
                for (int i = 0; i < 4; i++) Mm[i][j] /= cs;
            }
        }
        float gres = 0.f;
        for (int i = 0; i < 4; i++)
            for (int j = 0; j < 4; j++) gres += Mm[i][j];
        g_res_arr[row]  = gres;
        g_post_arr[row] = gpost;
        bcast = gpre;
    }
    __syncthreads();
    const float gpre = bcast;

    __hip_bfloat16* arow = Abuf + (size_t)row * DIM;
    ushort4 u0, u1;
    u0.x = f2bf(xv0.x * gpre); u0.y = f2bf(xv0.y * gpre);
    u0.z = f2bf(xv0.z * gpre); u0.w = f2bf(xv0.w * gpre);
    u1.x = f2bf(xv1.x * gpre); u1.y = f2bf(xv1.y * gpre);
    u1.z = f2bf(xv1.z * gpre); u1.w = f2bf(xv1.w * gpre);
    *reinterpret_cast<ushort4*>(arow + 4 * tid)        = u0;
    *reinterpret_cast<ushort4*>(arow + 1024 + 4 * tid) = u1;
}

// ---------------------------------------------------------------------------
// bf16 GEMM, m97 structure: 128x128 tile, BK=32, 4 waves (2x2), 16x16x32 MFMA,
// double-buffered LDS staged with global_load_lds width=16.
// C[M][N] = A[M][K] @ Bt[N][K]^T, fused epilogue.
//  MODE 1: outh = bf16(gelu_erf(acc + bias))
//  MODE 2: outf = x*g_res[row] + (acc + bias)*g_post[row]
// ---------------------------------------------------------------------------
#define BM 128
#define BN 128
#define BK 32

template <int MODE>
__global__ __launch_bounds__(256) void gemm_bf16(
    const __hip_bfloat16* __restrict__ A, const __hip_bfloat16* __restrict__ Bt,
    int M, int N, int K, const float* __restrict__ bias,
    __hip_bfloat16* __restrict__ outh, float* __restrict__ outf,
    const float* __restrict__ x, const float* __restrict__ g_res,
    const float* __restrict__ g_post) {
    __shared__ __align__(16) __hip_bfloat16 sA[2][BM * BK];
    __shared__ __align__(16) __hip_bfloat16 sB[2][BN * BK];

    const int m0 = blockIdx.x * BM;
    const int n0 = blockIdx.y * BN;
    const int tid = threadIdx.x;
    const int lane = tid & 63;
    const int wave = tid >> 6;
    const int wr = wave >> 1, wc = wave & 1;

    f32x4 acc[4][4];
#pragma unroll
    for (int m = 0; m < 4; m++)
#pragma unroll
        for (int n = 0; n < 4; n++) acc[m][n] = (f32x4){0.f, 0.f, 0.f, 0.f};

    const int nk = K / BK;

    auto stage = [&](int kt, int buf) {
#pragma unroll
        for (int i = 0; i < 2; i++) {
            int c = wave * 2 + i;                 // chunk: 512 bf16 = 1024 B
            int idx = c * 512 + lane * 8;         // linear bf16 idx in [BM][BK]
            int r = idx >> 5, col = idx & 31;
            async_copy16(A + (size_t)(m0 + r) * K + kt * BK + col, &sA[buf][c * 512]);
        }
#pragma unroll
        for (int i = 0; i < 2; i++) {
            int c = wave * 2 + i;
            int idx = c * 512 + lane * 8;
            int r = idx >> 5, col = idx & 31;
            async_copy16(Bt + (size_t)(n0 + r) * K + kt * BK + col, &sB[buf][c * 512]);
        }
    };

    stage(0, 0);
    for (int kt = 0; kt < nk; ++kt) {
        __syncthreads();                          // drains vmcnt: buf[kt&1] ready
        if (kt + 1 < nk) stage(kt + 1, (kt + 1) & 1);
        const int buf = kt & 1;
        const int kh = (lane >> 4) * 8;
        const int rA = wr * 64 + (lane & 15);
        const int rB = wc * 64 + (lane & 15);
        bf16x8 af[4], bfr[4];
#pragma unroll
        for (int m = 0; m < 4; m++)
            af[m] = *(const bf16x8*)(&sA[buf][(rA + m * 16) * BK + kh]);
#pragma unroll
        for (int n = 0; n < 4; n++)
            bfr[n] = *(const bf16x8*)(&sB[buf][(rB + n * 16) * BK + kh]);
#pragma unroll
        for (int m = 0; m < 4; m++)
#pragma unroll
            for (int n = 0; n < 4; n++)
                acc[m][n] = __builtin_amdgcn_mfma_f32_16x16x32_bf16(af[m], bfr[n], acc[m][n], 0, 0, 0);
    }

    const int crow0 = m0 + wr * 64;
    const int ccol0 = n0 + wc * 64;
#pragma unroll
    for (int m = 0; m < 4; m++) {
#pragma unroll
        for (int n = 0; n < 4; n++) {
            const int col = ccol0 + n * 16 + (lane & 15);
#pragma unroll
            for (int j = 0; j < 4; j++) {
                const int row = crow0 + m * 16 + (lane >> 4) * 4 + j;
                float v = acc[m][n][j] + bias[col];
                if (MODE == 1) {
                    v = 0.5f * v * (1.0f + erff(v * 0.70710678118654752f));
                    outh[(size_t)row * N + col] = __float2bfloat16(v);
                } else {
                    outf[(size_t)row * N + col] =
                        x[(size_t)row * N + col] * g_res[row] + v * g_post[row];
                }
            }
        }
    }
}

// ---------------------------------------------------------------------------
// Workspace layout (bytes):
//   W1T  bf16 [DFF][DIM]   33,554,432
//   W2T  bf16 [DIM][DFF]   33,554,432
//   Abuf bf16 [NROWS][DIM] 33,554,432
//   Hbuf bf16 [NROWS][DFF] 134,217,728
//   Wfold f32 [24][DIM]        196,608
//   g_res f32 [NROWS]           32,768
//   g_post f32 [NROWS]          32,768
// total ~235.2 MB
// ---------------------------------------------------------------------------
extern "C" void kernel_launch(void* const* d_in, const int* in_sizes, int n_in,
                              void* d_out, int out_size, void* d_ws, size_t ws_size,
                              hipStream_t stream) {
    const float* x          = (const float*)d_in[0];
    const float* phi_pre_w  = (const float*)d_in[1];
    const float* phi_pre_b  = (const float*)d_in[2];
    const float* phi_post_w = (const float*)d_in[3];
    const float* phi_post_b = (const float*)d_in[4];
    const float* phi_res_w  = (const float*)d_in[5];
    const float* phi_res_b  = (const float*)d_in[6];
    const float* alpha_pre  = (const float*)d_in[7];
    const float* alpha_post = (const float*)d_in[8];
    const float* alpha_res  = (const float*)d_in[9];
    const float* b_pre      = (const float*)d_in[10];
    const float* b_post     = (const float*)d_in[11];
    const float* b_res      = (const float*)d_in[12];
    const float* W1         = (const float*)d_in[13];
    const float* b1         = (const float*)d_in[14];
    const float* W2         = (const float*)d_in[15];
    const float* b2         = (const float*)d_in[16];
    float* out = (float*)d_out;

    char* ws = (char*)d_ws;
    __hip_bfloat16* W1T  = (__hip_bfloat16*)ws;                      // [DFF][DIM]
    __hip_bfloat16* W2T  = W1T + (size_t)DFF * DIM;                  // [DIM][DFF]
    __hip_bfloat16* Abuf = W2T + (size_t)DIM * DFF;                  // [NROWS][DIM]
    __hip_bfloat16* Hbuf = Abuf + (size_t)NROWS * DIM;               // [NROWS][DFF]
    float* Wfold = (float*)(Hbuf + (size_t)NROWS * DFF);             // [24][DIM]
    float* gres  = Wfold + NFOLD * DIM;
    float* gpost = gres + NROWS;

    fold_kernel<<<(NFOLD * DIM + 255) / 256, 256, 0, stream>>>(phi_pre_w, phi_post_w,
                                                               phi_res_w, Wfold);
    transpose_to_bf16<<<dim3(DFF / 32, DIM / 32), 256, 0, stream>>>(W1, W1T, DIM, DFF);
    transpose_to_bf16<<<dim3(DIM / 32, DFF / 32), 256, 0, stream>>>(W2, W2T, DFF, DIM);
    gating_kernel<<<NROWS, 256, 0, stream>>>(x, Wfold, phi_pre_b, phi_post_b, phi_res_b,
                                             alpha_pre, alpha_post, alpha_res,
                                             b_pre, b_post, b_res, Abuf, gres, gpost);
    gemm_bf16<1><<<dim3(NROWS / BM, DFF / BN), 256, 0, stream>>>(
        Abuf, W1T, NROWS, DFF, DIM, b1, Hbuf, nullptr, nullptr, nullptr, nullptr);
    gemm_bf16<2><<<dim3(NROWS / BM, DIM / BN), 256, 0, stream>>>(
        Hbuf, W2T, NROWS, DIM, DFF, b2, nullptr, out, x, gres, gpost);
}

// Round 2
// 887.627 us; speedup vs baseline: 1.2565x; 1.2565x over previous
//
#include <hip/hip_runtime.h>
#include <hip/hip_bf16.h>
#include <cstdint>
#include <cstddef>

// Problem constants (B=4, T=2048, DIM=2048, S=4, DFF=8192)
#define DIM   2048
#define DFF   8192
#define NROWS 8192   // B*T
#define NFOLD 24     // 4 (pre) + 4 (post) + 16 (res)

typedef float f32x4 __attribute__((ext_vector_type(4)));
typedef __bf16 bf16x8 __attribute__((ext_vector_type(8)));

__device__ __forceinline__ float sigmoidf_(float v) { return 1.0f / (1.0f + expf(-v)); }

__device__ __forceinline__ unsigned short f2bf(float v) {
    union { __hip_bfloat16 h; unsigned short u; } cv;
    cv.h = __float2bfloat16(v);
    return cv.u;
}

__device__ __forceinline__ void async_copy16(const void* g, void* l) {
    __builtin_amdgcn_global_load_lds((const __attribute__((address_space(1))) void*)g,
                                     (__attribute__((address_space(3))) void*)l, 16, 0, 0);
}

// Raw workgroup barrier WITHOUT waitcnt drain (keeps global_load_lds in flight).
// The empty asm is a compile-time memory fence only: stops the compiler from
// hoisting LDS reads / stage issues across the barrier; emits no instructions.
__device__ __forceinline__ void wg_barrier() {
    asm volatile("" ::: "memory");
    __builtin_amdgcn_s_barrier();
    asm volatile("" ::: "memory");
}

// ---------------------------------------------------------------------------
// Fold phi weights: Wfold[r][d] = sum_{j<4} src[r][j*DIM + d], r in [0,24)
// ---------------------------------------------------------------------------
__global__ __launch_bounds__(256) void fold_kernel(const float* __restrict__ pre_w,
                                                   const float* __restrict__ post_w,
                                                   const float* __restrict__ res_w,
                                                   float* __restrict__ Wfold) {
    int idx = blockIdx.x * 256 + threadIdx.x;
    if (idx >= NFOLD * DIM) return;
    int r = idx >> 11;          // /DIM
    int d = idx & (DIM - 1);
    const float* src;
    if (r < 4)      src = pre_w  + (size_t)r * (4 * DIM);
    else if (r < 8) src = post_w + (size_t)(r - 4) * (4 * DIM);
    else            src = res_w  + (size_t)(r - 8) * (4 * DIM);
    Wfold[idx] = src[d] + src[DIM + d] + src[2 * DIM + d] + src[3 * DIM + d];
}

// ---------------------------------------------------------------------------
// Transpose f32 [R][C] -> bf16 [C][R]
// ---------------------------------------------------------------------------
__global__ __launch_bounds__(256) void transpose_to_bf16(const float* __restrict__ in,
                                                         __hip_bfloat16* __restrict__ out,
                                                         int R, int C) {
    __shared__ float tile[32][33];
    int bx = blockIdx.x, by = blockIdx.y;
    int tx = threadIdx.x & 31, ty0 = threadIdx.x >> 5;
#pragma unroll
    for (int i = 0; i < 4; i++) {
        int ty = ty0 + i * 8;
        tile[ty][tx] = in[(size_t)(by * 32 + ty) * C + bx * 32 + tx];
    }
    __syncthreads();
#pragma unroll
    for (int i = 0; i < 4; i++) {
        int ty = ty0 + i * 8;
        out[(size_t)(bx * 32 + ty) * R + by * 32 + tx] = __float2bfloat16(tile[tx][ty]);
    }
}

// ---------------------------------------------------------------------------
// Gating: per row -> g_pre (folded into A = bf16(x*g_pre)), g_post, g_res
// ---------------------------------------------------------------------------
__global__ __launch_bounds__(256) void gating_kernel(
    const float* __restrict__ x, const float* __restrict__ Wfold,
    const float* __restrict__ phi_pre_b, const float* __restrict__ phi_post_b,
    const float* __restrict__ phi_res_b,
    const float* __restrict__ alpha_pre, const float* __restrict__ alpha_post,
    const float* __restrict__ alpha_res,
    const float* __restrict__ b_pre, const float* __restrict__ b_post,
    const float* __restrict__ b_res,
    __hip_bfloat16* __restrict__ Abuf,
    float* __restrict__ g_res_arr, float* __restrict__ g_post_arr) {
    const int row = blockIdx.x;
    const int tid = threadIdx.x;
    const int lane = tid & 63, wave = tid >> 6;

    const float4* xr = (const float4*)(x + (size_t)row * DIM);
    float4 xv0 = xr[tid];
    float4 xv1 = xr[tid + 256];

    float p[25];
    p[24] = xv0.x * xv0.x + xv0.y * xv0.y + xv0.z * xv0.z + xv0.w * xv0.w +
            xv1.x * xv1.x + xv1.y * xv1.y + xv1.z * xv1.z + xv1.w * xv1.w;
#pragma unroll
    for (int r = 0; r < NFOLD; r++) {
        const float4* w = (const float4*)(Wfold + (size_t)r * DIM);
        float4 w0 = w[tid], w1 = w[tid + 256];
        p[r] = xv0.x * w0.x + xv0.y * w0.y + xv0.z * w0.z + xv0.w * w0.w +
               xv1.x * w1.x + xv1.y * w1.y + xv1.z * w1.z + xv1.w * w1.w;
    }

    __shared__ float red[4][25];
    __shared__ float fin[25];
    __shared__ float bcast;
#pragma unroll
    for (int r = 0; r < 25; r++) {
        float v = p[r];
#pragma unroll
        for (int off = 32; off; off >>= 1) v += __shfl_down(v, off, 64);
        if (lane == 0) red[wave][r] = v;
    }
    __syncthreads();
    if (tid < 25) fin[tid] = red[0][tid] + red[1][tid] + red[2][tid] + red[3][tid];
    __syncthreads();
    if (tid == 0) {
        float rms = rsqrtf(fin[24] / (float)DIM + 1.1920928955078125e-07f);
        float ap = alpha_pre[0], aq = alpha_post[0], ar = alpha_res[0];
        float gpre = 0.f, gpost = 0.f;
#pragma unroll
        for (int s = 0; s < 4; s++) {
            gpre  += sigmoidf_(ap * (rms * fin[s]     + phi_pre_b[s])  + b_pre[s]);
            gpost += 2.0f * sigmoidf_(aq * (rms * fin[4 + s] + phi_post_b[s]) + b_post[s]);
        }
        float Mm[4][4];
#pragma unroll
        for (int i = 0; i < 4; i++)
#pragma unroll
            for (int j = 0; j < 4; j++) {
                int k = i * 4 + j;
                Mm[i][j] = expf(ar * (rms * fin[8 + k] + phi_res_b[k]) + b_res[k]);
            }
        for (int it = 0; it < 10; ++it) {
            for (int i = 0; i < 4; i++) {
                float rs = Mm[i][0] + Mm[i][1] + Mm[i][2] + Mm[i][3];
                for (int j = 0; j < 4; j++) Mm[i][j] /= rs;
            }
            for (int j = 0; j < 4; j++) {
                float cs = Mm[0][j] + Mm[1][j] + Mm[2][j] + Mm[3][j];
                for (int i = 0; i < 4; i++) Mm[i][j] /= cs;
            }
        }
        float gres = 0.f;
        for (int i = 0; i < 4; i++)
            for (int j = 0; j < 4; j++) gres += Mm[i][j];
        g_res_arr[row]  = gres;
        g_post_arr[row] = gpost;
        bcast = gpre;
    }
    __syncthreads();
    const float gpre = bcast;

    __hip_bfloat16* arow = Abuf + (size_t)row * DIM;
    ushort4 u0, u1;
    u0.x = f2bf(xv0.x * gpre); u0.y = f2bf(xv0.y * gpre);
    u0.z = f2bf(xv0.z * gpre); u0.w = f2bf(xv0.w * gpre);
    u1.x = f2bf(xv1.x * gpre); u1.y = f2bf(xv1.y * gpre);
    u1.z = f2bf(xv1.z * gpre); u1.w = f2bf(xv1.w * gpre);
    *reinterpret_cast<ushort4*>(arow + 4 * tid)        = u0;
    *reinterpret_cast<ushort4*>(arow + 1024 + 4 * tid) = u1;
}

// ---------------------------------------------------------------------------
// 256x256 bf16 GEMM, 4-phase schedule, counted vmcnt, XOR-swizzled LDS.
//   C[M][N] = A[M][K] @ Bt[N][K]^T
//   8 waves (2 M x 4 N), per-wave output 128x64, BK=64, LDS 128 KiB (2 buf).
// LDS layout per buffer: [256 rows][128 bytes], element (r, colbyte c) stored
// at byte r*128 + (c ^ ((r&7)<<4)). global_load_lds writes linearly; the
// inverse permutation is applied on the per-lane GLOBAL source address.
// Phase schedule per K-tile t (buffers: tile t in buf[t&1]):
//   P1: read A[m 0-3]+B[n 0-1]; stage A-half0(t+1); bar; 16 MFMA; bar
//   P2: read B[n 2-3];          stage A-half1(t+1); bar; 16 MFMA; bar
//   P3: read A[m 4-7];          stage B-half0(t+2); bar; 16 MFMA; bar
//   P4:                         stage B-half1(t+2);      16 MFMA; vmcnt(4); bar
// Safety: A(t+1) targets buf^1 (A region idle since t-1 P3 drain);
// B(t+2) targets buf's B region (dead after t P2 drain + barrier).
// vmcnt(4) keeps the 4 youngest loads (B(t+2)) in flight across the barrier.
// ---------------------------------------------------------------------------
#define RD_A(mh)                                                                 \
    _Pragma("unroll") for (int m = 0; m < 4; ++m) {                              \
        aR[m][0] = *(const bf16x8*)(sAc + baseA + ((mh) * 4 + m) * 2048 + cb0);  \
        aR[m][1] = *(const bf16x8*)(sAc + baseA + ((mh) * 4 + m) * 2048 + cb1);  \
    }

#define RD_B(nh)                                                                 \
    _Pragma("unroll") for (int n = 0; n < 2; ++n) {                              \
        bR[nh][n][0] = *(const bf16x8*)(sBc + baseB + ((nh) * 2 + n) * 2048 + cb0); \
        bR[nh][n][1] = *(const bf16x8*)(sBc + baseB + ((nh) * 2 + n) * 2048 + cb1); \
    }

#define MQ(mh, nh)                                                               \
    __builtin_amdgcn_s_setprio(1);                                               \
    _Pragma("unroll") for (int m = 0; m < 4; ++m)                                \
    _Pragma("unroll") for (int n = 0; n < 2; ++n) {                              \
        acc[(mh)*4+m][(nh)*2+n] = __builtin_amdgcn_mfma_f32_16x16x32_bf16(       \
            aR[m][0], bR[nh][n][0], acc[(mh)*4+m][(nh)*2+n], 0, 0, 0);           \
        acc[(mh)*4+m][(nh)*2+n] = __builtin_amdgcn_mfma_f32_16x16x32_bf16(       \
            aR[m][1], bR[nh][n][1], acc[(mh)*4+m][(nh)*2+n], 0, 0, 0);           \
    }                                                                            \
    __builtin_amdgcn_s_setprio(0);

#define STG(matb, srcArr, ldsb, t_, h_)                                          \
    if ((t_) < nk) {                                                             \
        char* l_ = (ldsb) + (((t_) & 1) * 32768) + (h_) * 16384 + wave * 1024;   \
        async_copy16((matb) + (size_t)srcArr[0][h_] + (size_t)(t_) * 128, l_);   \
        async_copy16((matb) + (size_t)srcArr[1][h_] + (size_t)(t_) * 128, l_ + 8192); \
    }

template <int MODE, int NTLOG>
__global__ __launch_bounds__(512, 2) void gemm256(
    const __hip_bfloat16* __restrict__ A, const __hip_bfloat16* __restrict__ Bt,
    int M, int N, int K, const float* __restrict__ bias,
    __hip_bfloat16* __restrict__ outh, float* __restrict__ outf,
    const float* __restrict__ x, const float* __restrict__ g_res,
    const float* __restrict__ g_post) {
    __shared__ __align__(16) char ldsA[65536];   // 2 buffers x [256][128B]
    __shared__ __align__(16) char ldsB[65536];

    // XCD-chunked bijective block swizzle (gridDim.x % 8 == 0 for our shapes)
    const int nwg = gridDim.x;
    const int wg = blockIdx.x;
    const int swz = (wg & 7) * (nwg >> 3) + (wg >> 3);
    const int mt = swz >> NTLOG;
    const int nt = swz & ((1 << NTLOG) - 1);
    const int m0 = mt * 256;
    const int n0 = nt * 256;

    const int tid = threadIdx.x;
    const int lane = tid & 63;
    const int wave = tid >> 6;            // 0..7
    const int wr = wave >> 2;             // 0..1 (M)
    const int wc = wave & 3;              // 0..3 (N)
    const int q = lane >> 4;              // 0..3
    const int rr = lane & 7;

    // ds_read addressing (bytes, within a 32KB buffer)
    const uint32_t cb0 = (uint32_t)((q ^ rr) << 4);         // ks=0
    const uint32_t cb1 = (uint32_t)(((4 + q) ^ rr) << 4);   // ks=1
    const uint32_t baseA = (uint32_t)((wr * 128 + (lane & 15)) * 128);
    const uint32_t baseB = (uint32_t)((wc * 64 + (lane & 15)) * 128);

    // staging source addressing (bytes from matrix base)
    const int srow = wave * 8 + (lane >> 3);                    // + i*64
    const uint32_t scb = (uint32_t)((((lane & 7) ^ ((lane >> 3) & 7))) << 4);
    uint32_t aSrc[2][2], bSrc[2][2];
#pragma unroll
    for (int i = 0; i < 2; ++i)
#pragma unroll
        for (int h = 0; h < 2; ++h) {
            aSrc[i][h] = (uint32_t)(m0 + h * 128 + i * 64 + srow) * (uint32_t)(K * 2) + scb;
            bSrc[i][h] = (uint32_t)(n0 + h * 128 + i * 64 + srow) * (uint32_t)(K * 2) + scb;
        }
    const char* Ab = (const char*)A;
    const char* Bb = (const char*)Bt;

    f32x4 acc[8][4];
#pragma unroll
    for (int m = 0; m < 8; ++m)
#pragma unroll
        for (int n = 0; n < 4; ++n) acc[m][n] = (f32x4){0.f, 0.f, 0.f, 0.f};

    const int nk = K / 64;

    // Prologue: stage tile0 (A,B) + tile1 (B); tile1's A comes in t=0 P1/P2.
    STG(Ab, aSrc, ldsA, 0, 0) STG(Ab, aSrc, ldsA, 0, 1)
    STG(Bb, bSrc, ldsB, 0, 0) STG(Bb, bSrc, ldsB, 0, 1)
    STG(Bb, bSrc, ldsB, 1, 0) STG(Bb, bSrc, ldsB, 1, 1)
    asm volatile("s_waitcnt vmcnt(4)" ::: "memory");   // tile0 complete; B(1) in flight
    wg_barrier();

    bf16x8 aR[4][2];
    bf16x8 bR[2][2][2];

    for (int kt = 0; kt < nk; ++kt) {
        const char* sAc = ldsA + (kt & 1) * 32768;
        const char* sBc = ldsB + (kt & 1) * 32768;
        // P1
        RD_A(0) RD_B(0)
        STG(Ab, aSrc, ldsA, kt + 1, 0)
        wg_barrier();
        MQ(0, 0)
        wg_barrier();
        // P2
        RD_B(1)
        STG(Ab, aSrc, ldsA, kt + 1, 1)
        wg_barrier();
        MQ(0, 1)
        wg_barrier();
        // P3
        RD_A(1)
        STG(Bb, bSrc, ldsB, kt + 2, 0)
        wg_barrier();
        MQ(1, 0)
        wg_barrier();
        // P4
        STG(Bb, bSrc, ldsB, kt + 2, 1)
        MQ(1, 1)
        if (kt + 1 < nk) {
            if (kt + 2 < nk) {
                asm volatile("s_waitcnt vmcnt(4)" ::: "memory");
            } else {
                asm volatile("s_waitcnt vmcnt(0)" ::: "memory");
            }
            wg_barrier();
        }
    }

    // Epilogue
    const int crow0 = m0 + wr * 128;
    const int ccol0 = n0 + wc * 64;
#pragma unroll
    for (int mi = 0; mi < 8; ++mi) {
#pragma unroll
        for (int ni = 0; ni < 4; ++ni) {
            const int col = ccol0 + ni * 16 + (lane & 15);
            const float bc = bias[col];
#pragma unroll
            for (int j = 0; j < 4; ++j) {
                const int row = crow0 + mi * 16 + q * 4 + j;
                float v = acc[mi][ni][j] + bc;
                if (MODE == 1) {
                    v = 0.5f * v * (1.0f + erff(v * 0.70710678118654752f));
                    outh[(size_t)row * N + col] = __float2bfloat16(v);
                } else {
                    outf[(size_t)row * N + col] =
                        x[(size_t)row * N + col] * g_res[row] + v * g_post[row];
                }
            }
        }
    }
}

// ---------------------------------------------------------------------------
// Workspace layout unchanged from round 0 (~235.2 MB)
// ---------------------------------------------------------------------------
extern "C" void kernel_launch(void* const* d_in, const int* in_sizes, int n_in,
                              void* d_out, int out_size, void* d_ws, size_t ws_size,
                              hipStream_t stream) {
    const float* x          = (const float*)d_in[0];
    const float* phi_pre_w  = (const float*)d_in[1];
    const float* phi_pre_b  = (const float*)d_in[2];
    const float* phi_post_w = (const float*)d_in[3];
    const float* phi_post_b = (const float*)d_in[4];
    const float* phi_res_w  = (const float*)d_in[5];
    const float* phi_res_b  = (const float*)d_in[6];
    const float* alpha_pre  = (const float*)d_in[7];
    const float* alpha_post = (const float*)d_in[8];
    const float* alpha_res  = (const float*)d_in[9];
    const float* b_pre      = (const float*)d_in[10];
    const float* b_post     = (const float*)d_in[11];
    const float* b_res      = (const float*)d_in[12];
    const float* W1         = (const float*)d_in[13];
    const float* b1         = (const float*)d_in[14];
    const float* W2         = (const float*)d_in[15];
    const float* b2         = (const float*)d_in[16];
    float* out = (float*)d_out;

    char* ws = (char*)d_ws;
    __hip_bfloat16* W1T  = (__hip_bfloat16*)ws;                      // [DFF][DIM]
    __hip_bfloat16* W2T  = W1T + (size_t)DFF * DIM;                  // [DIM][DFF]
    __hip_bfloat16* Abuf = W2T + (size_t)DIM * DFF;                  // [NROWS][DIM]
    __hip_bfloat16* Hbuf = Abuf + (size_t)NROWS * DIM;               // [NROWS][DFF]
    float* Wfold = (float*)(Hbuf + (size_t)NROWS * DFF);             // [24][DIM]
    float* gres  = Wfold + NFOLD * DIM;
    float* gpost = gres + NROWS;

    fold_kernel<<<(NFOLD * DIM + 255) / 256, 256, 0, stream>>>(phi_pre_w, phi_post_w,
                                                               phi_res_w, Wfold);
    transpose_to_bf16<<<dim3(DFF / 32, DIM / 32), 256, 0, stream>>>(W1, W1T, DIM, DFF);
    transpose_to_bf16<<<dim3(DIM / 32, DFF / 32), 256, 0, stream>>>(W2, W2T, DFF, DIM);
    gating_kernel<<<NROWS, 256, 0, stream>>>(x, Wfold, phi_pre_b, phi_post_b, phi_res_b,
                                             alpha_pre, alpha_post, alpha_res,
                                             b_pre, b_post, b_res, Abuf, gres, gpost);
    // GEMM1: [8192 x 2048] @ W1 -> gelu -> Hbuf [8192 x 8192]; grid 32x32=1024
    gemm256<1, 5><<<1024, 512, 0, stream>>>(
        Abuf, W1T, NROWS, DFF, DIM, b1, Hbuf, nullptr, nullptr, nullptr, nullptr);
    // GEMM2: [8192 x 8192] @ W2 -> out [8192 x 2048]; grid 32x8=256
    gemm256<2, 3><<<256, 512, 0, stream>>>(
        Hbuf, W2T, NROWS, DIM, DFF, b2, nullptr, out, x, gres, gpost);
}

// Round 3
// 762.089 us; speedup vs baseline: 1.4635x; 1.1647x over previous
//
#include <hip/hip_runtime.h>
#include <hip/hip_bf16.h>
#include <cstdint>
#include <cstddef>

// Problem constants (B=4, T=2048, DIM=2048, S=4, DFF=8192)
#define DIM   2048
#define DFF   8192
#define NROWS 8192   // B*T
#define NFOLD 24     // 4 (pre) + 4 (post) + 16 (res)

typedef float f32x4 __attribute__((ext_vector_type(4)));
typedef __bf16 bf16x8 __attribute__((ext_vector_type(8)));

__device__ __forceinline__ float sigmoidf_(float v) { return 1.0f / (1.0f + expf(-v)); }

__device__ __forceinline__ unsigned short f2bf(float v) {
    union { __hip_bfloat16 h; unsigned short u; } cv;
    cv.h = __float2bfloat16(v);
    return cv.u;
}

__device__ __forceinline__ void async_copy16(const void* g, void* l) {
    __builtin_amdgcn_global_load_lds((const __attribute__((address_space(1))) void*)g,
                                     (__attribute__((address_space(3))) void*)l, 16, 0, 0);
}

// Raw workgroup barrier WITHOUT waitcnt drain (keeps global_load_lds in flight).
__device__ __forceinline__ void wg_barrier() {
    asm volatile("" ::: "memory");
    __builtin_amdgcn_s_barrier();
    asm volatile("" ::: "memory");
}

// ---------------------------------------------------------------------------
// Fold phi weights: Wfold[r][d] = sum_{j<4} src[r][j*DIM + d], r in [0,24)
// ---------------------------------------------------------------------------
__global__ __launch_bounds__(256) void fold_kernel(const float* __restrict__ pre_w,
                                                   const float* __restrict__ post_w,
                                                   const float* __restrict__ res_w,
                                                   float* __restrict__ Wfold) {
    int idx = blockIdx.x * 256 + threadIdx.x;
    if (idx >= NFOLD * DIM) return;
    int r = idx >> 11;          // /DIM
    int d = idx & (DIM - 1);
    const float* src;
    if (r < 4)      src = pre_w  + (size_t)r * (4 * DIM);
    else if (r < 8) src = post_w + (size_t)(r - 4) * (4 * DIM);
    else            src = res_w  + (size_t)(r - 8) * (4 * DIM);
    Wfold[idx] = src[d] + src[DIM + d] + src[2 * DIM + d] + src[3 * DIM + d];
}

// ---------------------------------------------------------------------------
// Transpose f32 [R][C] -> bf16 [C][R]
// ---------------------------------------------------------------------------
__global__ __launch_bounds__(256) void transpose_to_bf16(const float* __restrict__ in,
                                                         __hip_bfloat16* __restrict__ out,
                                                         int R, int C) {
    __shared__ float tile[32][33];
    int bx = blockIdx.x, by = blockIdx.y;
    int tx = threadIdx.x & 31, ty0 = threadIdx.x >> 5;
#pragma unroll
    for (int i = 0; i < 4; i++) {
        int ty = ty0 + i * 8;
        tile[ty][tx] = in[(size_t)(by * 32 + ty) * C + bx * 32 + tx];
    }
    __syncthreads();
#pragma unroll
    for (int i = 0; i < 4; i++) {
        int ty = ty0 + i * 8;
        out[(size_t)(bx * 32 + ty) * R + by * 32 + tx] = __float2bfloat16(tile[tx][ty]);
    }
}

// ---------------------------------------------------------------------------
// Gating: wave-per-row, 8 rows per block (512 threads). Each lane holds 32
// floats of its row (chunk-strided, coalesced); Wfold streamed once per block
// and shared across the 8 waves via L1. All-lane-redundant sinkhorn (wave-
// uniform, no serial lane-0 section, no broadcast needed).
// ---------------------------------------------------------------------------
__global__ __launch_bounds__(512) void gating_kernel(
    const float* __restrict__ x, const float* __restrict__ Wfold,
    const float* __restrict__ phi_pre_b, const float* __restrict__ phi_post_b,
    const float* __restrict__ phi_res_b,
    const float* __restrict__ alpha_pre, const float* __restrict__ alpha_post,
    const float* __restrict__ alpha_res,
    const float* __restrict__ b_pre, const float* __restrict__ b_post,
    const float* __restrict__ b_res,
    __hip_bfloat16* __restrict__ Abuf,
    float* __restrict__ g_res_arr, float* __restrict__ g_post_arr) {
    const int tid = threadIdx.x;
    const int lane = tid & 63, wave = tid >> 6;
    const int row = blockIdx.x * 8 + wave;

    const float4* x4 = (const float4*)x + (size_t)row * 512;
    const float4* w4 = (const float4*)Wfold;

    float4 xv[8];
#pragma unroll
    for (int j = 0; j < 8; j++) xv[j] = x4[j * 64 + lane];

    float p[25];
    p[24] = 0.f;
#pragma unroll
    for (int j = 0; j < 8; j++)
        p[24] += xv[j].x * xv[j].x + xv[j].y * xv[j].y + xv[j].z * xv[j].z + xv[j].w * xv[j].w;

    for (int r = 0; r < NFOLD; r++) {
        float acc = 0.f;
#pragma unroll
        for (int j = 0; j < 8; j++) {
            float4 wv = w4[r * 512 + j * 64 + lane];
            acc += xv[j].x * wv.x + xv[j].y * wv.y + xv[j].z * wv.z + xv[j].w * wv.w;
        }
        p[r] = acc;
    }

    // 64-lane butterfly reduce; every lane ends with the full sums.
#pragma unroll
    for (int r = 0; r < 25; r++) {
        float v = p[r];
#pragma unroll
        for (int off = 1; off < 64; off <<= 1) v += __shfl_xor(v, off, 64);
        p[r] = v;
    }

    const float rms = rsqrtf(p[24] / (float)DIM + 1.1920928955078125e-07f);
    const float ap = alpha_pre[0], aq = alpha_post[0], ar = alpha_res[0];
    float gpre = 0.f, gpost = 0.f;
#pragma unroll
    for (int s = 0; s < 4; s++) {
        gpre  += sigmoidf_(ap * (rms * p[s]     + phi_pre_b[s])  + b_pre[s]);
        gpost += 2.0f * sigmoidf_(aq * (rms * p[4 + s] + phi_post_b[s]) + b_post[s]);
    }
    float Mm[4][4];
#pragma unroll
    for (int i = 0; i < 4; i++)
#pragma unroll
        for (int j = 0; j < 4; j++) {
            int k = i * 4 + j;
            Mm[i][j] = expf(ar * (rms * p[8 + k] + phi_res_b[k]) + b_res[k]);
        }
    for (int it = 0; it < 10; ++it) {
#pragma unroll
        for (int i = 0; i < 4; i++) {
            float rs = 1.0f / (Mm[i][0] + Mm[i][1] + Mm[i][2] + Mm[i][3]);
#pragma unroll
            for (int j = 0; j < 4; j++) Mm[i][j] *= rs;
        }
#pragma unroll
        for (int j = 0; j < 4; j++) {
            float cs = 1.0f / (Mm[0][j] + Mm[1][j] + Mm[2][j] + Mm[3][j]);
#pragma unroll
            for (int i = 0; i < 4; i++) Mm[i][j] *= cs;
        }
    }
    float gres = 0.f;
#pragma unroll
    for (int i = 0; i < 4; i++)
#pragma unroll
        for (int j = 0; j < 4; j++) gres += Mm[i][j];

    __hip_bfloat16* arow = Abuf + (size_t)row * DIM;
#pragma unroll
    for (int j = 0; j < 8; j++) {
        ushort4 u;
        u.x = f2bf(xv[j].x * gpre); u.y = f2bf(xv[j].y * gpre);
        u.z = f2bf(xv[j].z * gpre); u.w = f2bf(xv[j].w * gpre);
        *reinterpret_cast<ushort4*>(arow + (j * 64 + lane) * 4) = u;
    }
    if (lane == 0) {
        g_res_arr[row]  = gres;
        g_post_arr[row] = gpost;
    }
}

// ---------------------------------------------------------------------------
// 256x256 bf16 GEMM, 4-phase schedule with ONE-PHASE-AHEAD register pipeline,
// counted vmcnt, XOR-swizzled LDS.  C[M][N] = A[M][K] @ Bt[N][K]^T.
// 8 waves (2 M x 4 N), per-wave output 128x64, BK=64, LDS 128 KiB (2 buf).
//
// Fragment register sets: a0/a1 (A halves), b0/b1 (B halves). Every MFMA
// consumes fragments read >=1 phase earlier, so LDS latency + port time hides
// under the previous phase's MFMA cluster:
//   pre : read a0,b0 of tile 0
//   P1: read b1(t);  stage A(t+1)h0; bar; MFMA(a0,b0); bar
//   P2: read a1(t);  stage A(t+1)h1; bar; MFMA(a0,b1); bar
//   P3:              stage B(t+2)h0; bar; MFMA(a1,b0); bar
//   P4:              stage B(t+2)h1; vmcnt(4); bar; read a0,b0 of t+1 (buf^1);
//                    MFMA(a1,b1)
// vmcnt audit (per-wave FIFO): at P4, outstanding = B(t+1)[4] A(t+1)[4]
// B(t+2)[4] = 12; vmcnt(4) drains the 8 oldest (exactly what the P4 reads
// need), keeps B(t+2) in flight. Tail (kt+2>=nk): vmcnt(0).
// ---------------------------------------------------------------------------
#define RDA(DST, SRC, mh)                                                        \
    _Pragma("unroll") for (int m = 0; m < 4; ++m) {                              \
        DST[m][0] = *(const bf16x8*)((SRC) + baseA + ((mh) * 4 + m) * 2048 + cb0); \
        DST[m][1] = *(const bf16x8*)((SRC) + baseA + ((mh) * 4 + m) * 2048 + cb1); \
    }

#define RDB(DST, SRC, nh)                                                        \
    _Pragma("unroll") for (int n = 0; n < 2; ++n) {                              \
        DST[n][0] = *(const bf16x8*)((SRC) + baseB + ((nh) * 2 + n) * 2048 + cb0); \
        DST[n][1] = *(const bf16x8*)((SRC) + baseB + ((nh) * 2 + n) * 2048 + cb1); \
    }

#define MQP(AREG, BREG, mh, nh)                                                  \
    __builtin_amdgcn_s_setprio(1);                                               \
    _Pragma("unroll") for (int m = 0; m < 4; ++m)                                \
    _Pragma("unroll") for (int n = 0; n < 2; ++n) {                              \
        acc[(mh)*4+m][(nh)*2+n] = __builtin_amdgcn_mfma_f32_16x16x32_bf16(       \
            AREG[m][0], BREG[n][0], acc[(mh)*4+m][(nh)*2+n], 0, 0, 0);           \
        acc[(mh)*4+m][(nh)*2+n] = __builtin_amdgcn_mfma_f32_16x16x32_bf16(       \
            AREG[m][1], BREG[n][1], acc[(mh)*4+m][(nh)*2+n], 0, 0, 0);           \
    }                                                                            \
    __builtin_amdgcn_s_setprio(0);

#define STG(matb, srcArr, ldsb, t_, h_)                                          \
    if ((t_) < nk) {                                                             \
        char* l_ = (ldsb) + (((t_) & 1) * 32768) + (h_) * 16384 + wave * 1024;   \
        async_copy16((matb) + (size_t)srcArr[0][h_] + (size_t)(t_) * 128, l_);   \
        async_copy16((matb) + (size_t)srcArr[1][h_] + (size_t)(t_) * 128, l_ + 8192); \
    }

template <int MODE, int NTLOG>
__global__ __launch_bounds__(512, 2) void gemm256(
    const __hip_bfloat16* __restrict__ A, const __hip_bfloat16* __restrict__ Bt,
    int M, int N, int K, const float* __restrict__ bias,
    __hip_bfloat16* __restrict__ outh, float* __restrict__ outf,
    const float* __restrict__ x, const float* __restrict__ g_res,
    const float* __restrict__ g_post) {
    __shared__ __align__(16) char ldsA[65536];   // 2 buffers x [256][128B]
    __shared__ __align__(16) char ldsB[65536];

    // XCD-chunked bijective block swizzle (gridDim.x % 8 == 0 for our shapes)
    const int nwg = gridDim.x;
    const int wg = blockIdx.x;
    const int swz = (wg & 7) * (nwg >> 3) + (wg >> 3);
    const int mt = swz >> NTLOG;
    const int nt = swz & ((1 << NTLOG) - 1);
    const int m0 = mt * 256;
    const int n0 = nt * 256;

    const int tid = threadIdx.x;
    const int lane = tid & 63;
    const int wave = tid >> 6;            // 0..7
    const int wr = wave >> 2;             // 0..1 (M)
    const int wc = wave & 3;              // 0..3 (N)
    const int q = lane >> 4;              // 0..3
    const int rr = lane & 7;

    // ds_read addressing (bytes, within a 32KB buffer)
    const uint32_t cb0 = (uint32_t)((q ^ rr) << 4);         // ks=0
    const uint32_t cb1 = (uint32_t)(((4 + q) ^ rr) << 4);   // ks=1
    const uint32_t baseA = (uint32_t)((wr * 128 + (lane & 15)) * 128);
    const uint32_t baseB = (uint32_t)((wc * 64 + (lane & 15)) * 128);

    // staging source addressing (bytes from matrix base)
    const int srow = wave * 8 + (lane >> 3);                    // + i*64
    const uint32_t scb = (uint32_t)((((lane & 7) ^ ((lane >> 3) & 7))) << 4);
    uint32_t aSrc[2][2], bSrc[2][2];
#pragma unroll
    for (int i = 0; i < 2; ++i)
#pragma unroll
        for (int h = 0; h < 2; ++h) {
            aSrc[i][h] = (uint32_t)(m0 + h * 128 + i * 64 + srow) * (uint32_t)(K * 2) + scb;
            bSrc[i][h] = (uint32_t)(n0 + h * 128 + i * 64 + srow) * (uint32_t)(K * 2) + scb;
        }
    const char* Ab = (const char*)A;
    const char* Bb = (const char*)Bt;

    f32x4 acc[8][4];
#pragma unroll
    for (int m = 0; m < 8; ++m)
#pragma unroll
        for (int n = 0; n < 4; ++n) acc[m][n] = (f32x4){0.f, 0.f, 0.f, 0.f};

    const int nk = K / 64;

    // Prologue: stage tile0 (A,B) + tile1 (B); wait tile0; preload a0/b0.
    STG(Ab, aSrc, ldsA, 0, 0) STG(Ab, aSrc, ldsA, 0, 1)
    STG(Bb, bSrc, ldsB, 0, 0) STG(Bb, bSrc, ldsB, 0, 1)
    STG(Bb, bSrc, ldsB, 1, 0) STG(Bb, bSrc, ldsB, 1, 1)
    asm volatile("s_waitcnt vmcnt(4)" ::: "memory");   // tile0 complete; B(1) in flight
    wg_barrier();

    bf16x8 a0[4][2], a1[4][2];
    bf16x8 b0[2][2], b1[2][2];
    RDA(a0, ldsA, 0)
    RDB(b0, ldsB, 0)

    for (int kt = 0; kt < nk; ++kt) {
        const char* sA  = ldsA + (kt & 1) * 32768;
        const char* sB  = ldsB + (kt & 1) * 32768;
        const char* sAn = ldsA + ((kt + 1) & 1) * 32768;
        const char* sBn = ldsB + ((kt + 1) & 1) * 32768;
        // P1
        RDB(b1, sB, 1)
        STG(Ab, aSrc, ldsA, kt + 1, 0)
        wg_barrier();
        MQP(a0, b0, 0, 0)
        wg_barrier();
        // P2
        RDA(a1, sA, 1)
        STG(Ab, aSrc, ldsA, kt + 1, 1)
        wg_barrier();
        MQP(a0, b1, 0, 1)
        wg_barrier();
        // P3
        STG(Bb, bSrc, ldsB, kt + 2, 0)
        wg_barrier();
        MQP(a1, b0, 1, 0)
        wg_barrier();
        // P4
        STG(Bb, bSrc, ldsB, kt + 2, 1)
        if (kt + 2 < nk) {
            asm volatile("s_waitcnt vmcnt(4)" ::: "memory");
        } else if (kt + 1 < nk) {
            asm volatile("s_waitcnt vmcnt(0)" ::: "memory");
        }
        wg_barrier();
        if (kt + 1 < nk) {
            RDA(a0, sAn, 0)
            RDB(b0, sBn, 0)
        }
        MQP(a1, b1, 1, 1)
        // no trailing barrier: next P1's barrier (after read+stage issue) covers it
    }

    // Epilogue
    const int crow0 = m0 + wr * 128;
    const int ccol0 = n0 + wc * 64;
#pragma unroll
    for (int mi = 0; mi < 8; ++mi) {
#pragma unroll
        for (int ni = 0; ni < 4; ++ni) {
            const int col = ccol0 + ni * 16 + (lane & 15);
            const float bc = bias[col];
#pragma unroll
            for (int j = 0; j < 4; ++j) {
                const int row = crow0 + mi * 16 + q * 4 + j;
                float v = acc[mi][ni][j] + bc;
                if (MODE == 1) {
                    // tanh-form GELU via fast exp (max dev vs erf-GELU ~3e-4)
                    float u = 1.5957691216057308f * (v + 0.044715f * v * v * v);
                    float s = 1.0f / (1.0f + __expf(-u));
                    outh[(size_t)row * N + col] = __float2bfloat16(v * s);
                } else {
                    outf[(size_t)row * N + col] =
                        x[(size_t)row * N + col] * g_res[row] + v * g_post[row];
                }
            }
        }
    }
}

// ---------------------------------------------------------------------------
// Workspace layout (~235.2 MB): W1T, W2T, Abuf, Hbuf, Wfold, gres, gpost
// ---------------------------------------------------------------------------
extern "C" void kernel_launch(void* const* d_in, const int* in_sizes, int n_in,
                              void* d_out, int out_size, void* d_ws, size_t ws_size,
                              hipStream_t stream) {
    const float* x          = (const float*)d_in[0];
    const float* phi_pre_w  = (const float*)d_in[1];
    const float* phi_pre_b  = (const float*)d_in[2];
    const float* phi_post_w = (const float*)d_in[3];
    const float* phi_post_b = (const float*)d_in[4];
    const float* phi_res_w  = (const float*)d_in[5];
    const float* phi_res_b  = (const float*)d_in[6];
    const float* alpha_pre  = (const float*)d_in[7];
    const float* alpha_post = (const float*)d_in[8];
    const float* alpha_res  = (const float*)d_in[9];
    const float* b_pre      = (const float*)d_in[10];
    const float* b_post     = (const float*)d_in[11];
    const float* b_res      = (const float*)d_in[12];
    const float* W1         = (const float*)d_in[13];
    const float* b1         = (const float*)d_in[14];
    const float* W2         = (const float*)d_in[15];
    const float* b2         = (const float*)d_in[16];
    float* out = (float*)d_out;

    char* ws = (char*)d_ws;
    __hip_bfloat16* W1T  = (__hip_bfloat16*)ws;                      // [DFF][DIM]
    __hip_bfloat16* W2T  = W1T + (size_t)DFF * DIM;                  // [DIM][DFF]
    __hip_bfloat16* Abuf = W2T + (size_t)DIM * DFF;                  // [NROWS][DIM]
    __hip_bfloat16* Hbuf = Abuf + (size_t)NROWS * DIM;               // [NROWS][DFF]
    float* Wfold = (float*)(Hbuf + (size_t)NROWS * DFF);             // [24][DIM]
    float* gres  = Wfold + NFOLD * DIM;
    float* gpost = gres + NROWS;

    fold_kernel<<<(NFOLD * DIM + 255) / 256, 256, 0, stream>>>(phi_pre_w, phi_post_w,
                                                               phi_res_w, Wfold);
    transpose_to_bf16<<<dim3(DFF / 32, DIM / 32), 256, 0, stream>>>(W1, W1T, DIM, DFF);
    transpose_to_bf16<<<dim3(DIM / 32, DFF / 32), 256, 0, stream>>>(W2, W2T, DFF, DIM);
    gating_kernel<<<NROWS / 8, 512, 0, stream>>>(x, Wfold, phi_pre_b, phi_post_b, phi_res_b,
                                                 alpha_pre, alpha_post, alpha_res,
                                                 b_pre, b_post, b_res, Abuf, gres, gpost);
    // GEMM1: [8192 x 2048] @ W1 -> gelu -> Hbuf [8192 x 8192]; grid 32x32=1024
    gemm256<1, 5><<<1024, 512, 0, stream>>>(
        Abuf, W1T, NROWS, DFF, DIM, b1, Hbuf, nullptr, nullptr, nullptr, nullptr);
    // GEMM2: [8192 x 8192] @ W2 -> out [8192 x 2048]; grid 32x8=256
    gemm256<2, 3><<<256, 512, 0, stream>>>(
        Hbuf, W2T, NROWS, DIM, DFF, b2, nullptr, out, x, gres, gpost);
}

// Round 5
// 721.125 us; speedup vs baseline: 1.5466x; 1.0568x over previous
//
#include <hip/hip_runtime.h>
#include <hip/hip_bf16.h>
#include <cstdint>
#include <cstddef>

// Problem constants (B=4, T=2048, DIM=2048, S=4, DFF=8192)
#define DIM   2048
#define DFF   8192
#define NROWS 8192   // B*T
#define NFOLD 24     // 4 (pre) + 4 (post) + 16 (res)

typedef float f32x4 __attribute__((ext_vector_type(4)));
typedef __bf16 bf16x8 __attribute__((ext_vector_type(8)));

__device__ __forceinline__ float sigmoidf_(float v) { return 1.0f / (1.0f + expf(-v)); }

__device__ __forceinline__ unsigned short f2bf(float v) {
    union { __hip_bfloat16 h; unsigned short u; } cv;
    cv.h = __float2bfloat16(v);
    return cv.u;
}

__device__ __forceinline__ void async_copy16(const void* g, void* l) {
    __builtin_amdgcn_global_load_lds((const __attribute__((address_space(1))) void*)g,
                                     (__attribute__((address_space(3))) void*)l, 16, 0, 0);
}

// Raw workgroup barrier WITHOUT waitcnt drain (keeps global_load_lds in flight).
__device__ __forceinline__ void wg_barrier() {
    asm volatile("" ::: "memory");
    __builtin_amdgcn_s_barrier();
    asm volatile("" ::: "memory");
}

#define VM(n) asm volatile("s_waitcnt vmcnt(" #n ")" ::: "memory")
// RACE FIX (round 4 post-mortem): force this wave's ds_reads to COMPLETE
// before crossing the phase-closing barrier. Without this, hipcc may sink the
// consuming MFMAs (register-only ops, rule #18) past the barrier, leaving the
// ds_read in flight while another wave's staging overwrites the same region.
#define LGKM0 asm volatile("s_waitcnt lgkmcnt(0)" ::: "memory")

// ---------------------------------------------------------------------------
// Fold phi weights: Wfold[r][d] = sum_{j<4} src[r][j*DIM + d], r in [0,24)
// ---------------------------------------------------------------------------
__global__ __launch_bounds__(256) void fold_kernel(const float* __restrict__ pre_w,
                                                   const float* __restrict__ post_w,
                                                   const float* __restrict__ res_w,
                                                   float* __restrict__ Wfold) {
    int idx = blockIdx.x * 256 + threadIdx.x;
    if (idx >= NFOLD * DIM) return;
    int r = idx >> 11;          // /DIM
    int d = idx & (DIM - 1);
    const float* src;
    if (r < 4)      src = pre_w  + (size_t)r * (4 * DIM);
    else if (r < 8) src = post_w + (size_t)(r - 4) * (4 * DIM);
    else            src = res_w  + (size_t)(r - 8) * (4 * DIM);
    Wfold[idx] = src[d] + src[DIM + d] + src[2 * DIM + d] + src[3 * DIM + d];
}

// ---------------------------------------------------------------------------
// Transpose f32 [R][C] -> bf16 [C][R]
// ---------------------------------------------------------------------------
__global__ __launch_bounds__(256) void transpose_to_bf16(const float* __restrict__ in,
                                                         __hip_bfloat16* __restrict__ out,
                                                         int R, int C) {
    __shared__ float tile[32][33];
    int bx = blockIdx.x, by = blockIdx.y;
    int tx = threadIdx.x & 31, ty0 = threadIdx.x >> 5;
#pragma unroll
    for (int i = 0; i < 4; i++) {
        int ty = ty0 + i * 8;
        tile[ty][tx] = in[(size_t)(by * 32 + ty) * C + bx * 32 + tx];
    }
    __syncthreads();
#pragma unroll
    for (int i = 0; i < 4; i++) {
        int ty = ty0 + i * 8;
        out[(size_t)(bx * 32 + ty) * R + by * 32 + tx] = __float2bfloat16(tile[tx][ty]);
    }
}

// ---------------------------------------------------------------------------
// Gating: wave-per-row, 8 rows per block (512 threads).
// ---------------------------------------------------------------------------
__global__ __launch_bounds__(512) void gating_kernel(
    const float* __restrict__ x, const float* __restrict__ Wfold,
    const float* __restrict__ phi_pre_b, const float* __restrict__ phi_post_b,
    const float* __restrict__ phi_res_b,
    const float* __restrict__ alpha_pre, const float* __restrict__ alpha_post,
    const float* __restrict__ alpha_res,
    const float* __restrict__ b_pre, const float* __restrict__ b_post,
    const float* __restrict__ b_res,
    __hip_bfloat16* __restrict__ Abuf,
    float* __restrict__ g_res_arr, float* __restrict__ g_post_arr) {
    const int tid = threadIdx.x;
    const int lane = tid & 63, wave = tid >> 6;
    const int row = blockIdx.x * 8 + wave;

    const float4* x4 = (const float4*)x + (size_t)row * 512;
    const float4* w4 = (const float4*)Wfold;

    float4 xv[8];
#pragma unroll
    for (int j = 0; j < 8; j++) xv[j] = x4[j * 64 + lane];

    float p[25];
    p[24] = 0.f;
#pragma unroll
    for (int j = 0; j < 8; j++)
        p[24] += xv[j].x * xv[j].x + xv[j].y * xv[j].y + xv[j].z * xv[j].z + xv[j].w * xv[j].w;

    for (int r = 0; r < NFOLD; r++) {
        float acc = 0.f;
#pragma unroll
        for (int j = 0; j < 8; j++) {
            float4 wv = w4[r * 512 + j * 64 + lane];
            acc += xv[j].x * wv.x + xv[j].y * wv.y + xv[j].z * wv.z + xv[j].w * wv.w;
        }
        p[r] = acc;
    }

#pragma unroll
    for (int r = 0; r < 25; r++) {
        float v = p[r];
#pragma unroll
        for (int off = 1; off < 64; off <<= 1) v += __shfl_xor(v, off, 64);
        p[r] = v;
    }

    const float rms = rsqrtf(p[24] / (float)DIM + 1.1920928955078125e-07f);
    const float ap = alpha_pre[0], aq = alpha_post[0], ar = alpha_res[0];
    float gpre = 0.f, gpost = 0.f;
#pragma unroll
    for (int s = 0; s < 4; s++) {
        gpre  += sigmoidf_(ap * (rms * p[s]     + phi_pre_b[s])  + b_pre[s]);
        gpost += 2.0f * sigmoidf_(aq * (rms * p[4 + s] + phi_post_b[s]) + b_post[s]);
    }
    float Mm[4][4];
#pragma unroll
    for (int i = 0; i < 4; i++)
#pragma unroll
        for (int j = 0; j < 4; j++) {
            int k = i * 4 + j;
            Mm[i][j] = expf(ar * (rms * p[8 + k] + phi_res_b[k]) + b_res[k]);
        }
    for (int it = 0; it < 10; ++it) {
#pragma unroll
        for (int i = 0; i < 4; i++) {
            float rs = 1.0f / (Mm[i][0] + Mm[i][1] + Mm[i][2] + Mm[i][3]);
#pragma unroll
            for (int j = 0; j < 4; j++) Mm[i][j] *= rs;
        }
#pragma unroll
        for (int j = 0; j < 4; j++) {
            float cs = 1.0f / (Mm[0][j] + Mm[1][j] + Mm[2][j] + Mm[3][j]);
#pragma unroll
            for (int i = 0; i < 4; i++) Mm[i][j] *= cs;
        }
    }
    float gres = 0.f;
#pragma unroll
    for (int i = 0; i < 4; i++)
#pragma unroll
        for (int j = 0; j < 4; j++) gres += Mm[i][j];

    __hip_bfloat16* arow = Abuf + (size_t)row * DIM;
#pragma unroll
    for (int j = 0; j < 8; j++) {
        ushort4 u;
        u.x = f2bf(xv[j].x * gpre); u.y = f2bf(xv[j].y * gpre);
        u.z = f2bf(xv[j].z * gpre); u.w = f2bf(xv[j].w * gpre);
        *reinterpret_cast<ushort4*>(arow + (j * 64 + lane) * 4) = u;
    }
    if (lane == 0) {
        g_res_arr[row]  = gres;
        g_post_arr[row] = gpost;
    }
}

// ---------------------------------------------------------------------------
// 256x256 bf16 GEMM, 4-phase schedule with a 6-PHASE-LEAD half-tile ring.
//   C[M][N] = A[M][K] @ Bt[N][K]^T; 8 waves (2M x 4N); per-wave out 128x64;
//   BK=64; LDS 128 KiB = 2 parities x 2 units x 16 KB, per A and B.
//
// Units are READ-ALIGNED 16 KB interleaves (rows given relative to tile):
//   A-even (h=0): rows {0-63, 128-191}   -- consumed by P1 (a0)
//   A-odd  (h=1): rows {64-127, 192-255} -- consumed by P3 (a1)
//   B-even (h=0): n-rows {0-31,64-95,128-159,192-223}  -- P1 (b0)
//   B-odd  (h=1): +32                                   -- P2 (b1)
// LDS region [128 rows][128 B]; row r at r*128, byte col ^ ((r&7)<<4);
// global_load_lds writes linearly; inverse XOR applied on per-lane global src.
//
// Phase p of tile t:  {ds_reads(p); stage units for t+2; counted vmcnt;
//                      bar; 16 MFMA; LGKM0; bar}
//   P1: read a0+b0; no stage;          vmcnt(10)   [drains Bo(t) for P2]
//   P2: read b1;    stage Ae,Be(t+2);  vmcnt(12)   [drains Ao(t) for P3]
//   P3: read a1;    stage Bo(t+2);     --
//   P4: --          stage Ao(t+2);     vmcnt(12)   [drains Ae,Be(t+1) for P1]
// LGKM0 before each read-phase's closing barrier guarantees the region's
// reads completed before ANY wave can issue the region's t+2 overwrite
// (issued in the next phase) -- independent of compiler MFMA placement.
// Tail: P1 vmcnt(2) @kt=nk-1; P2 vmcnt(8)/@last 0; P4 vmcnt(4), none @last.
// ---------------------------------------------------------------------------
#define RD_A0                                                                     \
    _Pragma("unroll") for (int m = 0; m < 4; ++m) {                               \
        a0[m][0] = *(const bf16x8*)(A0r + baseA + m * 2048 + cb0);                \
        a0[m][1] = *(const bf16x8*)(A0r + baseA + m * 2048 + cb1);                \
    }
#define RD_A1                                                                     \
    _Pragma("unroll") for (int m = 0; m < 4; ++m) {                               \
        a1[m][0] = *(const bf16x8*)(A1r + baseA + m * 2048 + cb0);                \
        a1[m][1] = *(const bf16x8*)(A1r + baseA + m * 2048 + cb1);                \
    }
#define RD_B0                                                                     \
    _Pragma("unroll") for (int n = 0; n < 2; ++n) {                               \
        b0[n][0] = *(const bf16x8*)(B0r + baseB + n * 2048 + cb0);                \
        b0[n][1] = *(const bf16x8*)(B0r + baseB + n * 2048 + cb1);                \
    }
#define RD_B1                                                                     \
    _Pragma("unroll") for (int n = 0; n < 2; ++n) {                               \
        b1[n][0] = *(const bf16x8*)(B1r + baseB + n * 2048 + cb0);                \
        b1[n][1] = *(const bf16x8*)(B1r + baseB + n * 2048 + cb1);                \
    }

#define MQ(AF, BF, MO, NO)                                                        \
    __builtin_amdgcn_s_setprio(1);                                                \
    _Pragma("unroll") for (int m = 0; m < 4; ++m)                                 \
    _Pragma("unroll") for (int n = 0; n < 2; ++n) {                               \
        acc[(MO) + m][(NO) + n] = __builtin_amdgcn_mfma_f32_16x16x32_bf16(        \
            AF[m][0], BF[n][0], acc[(MO) + m][(NO) + n], 0, 0, 0);                \
        acc[(MO) + m][(NO) + n] = __builtin_amdgcn_mfma_f32_16x16x32_bf16(        \
            AF[m][1], BF[n][1], acc[(MO) + m][(NO) + n], 0, 0, 0);                \
    }                                                                             \
    __builtin_amdgcn_s_setprio(0);

#define STG_A(t_, h_)                                                             \
    if ((t_) < nk) {                                                              \
        char* l_ = ldsA + (((t_) & 1) * 32768) + (h_) * 16384 + wave * 1024;      \
        async_copy16(Ab + aOff[0][h_] + (size_t)(t_) * 128, l_);                  \
        async_copy16(Ab + aOff[1][h_] + (size_t)(t_) * 128, l_ + 8192);           \
    }
#define STG_B(t_, h_)                                                             \
    if ((t_) < nk) {                                                              \
        char* l_ = ldsB + (((t_) & 1) * 32768) + (h_) * 16384 + wave * 1024;      \
        async_copy16(Bb + bOff[0][h_] + (size_t)(t_) * 128, l_);                  \
        async_copy16(Bb + bOff[1][h_] + (size_t)(t_) * 128, l_ + 8192);           \
    }

template <int MODE, int NB>
__global__ __launch_bounds__(512, 2) void gemm256(
    const __hip_bfloat16* __restrict__ A, const __hip_bfloat16* __restrict__ Bt,
    int M, int N, int K, const float* __restrict__ bias,
    __hip_bfloat16* __restrict__ outh, float* __restrict__ outf,
    const float* __restrict__ x, const float* __restrict__ g_res,
    const float* __restrict__ g_post) {
    __shared__ __align__(16) char ldsA[65536];
    __shared__ __align__(16) char ldsB[65536];

    // XCD band swizzle: each XCD owns an NB-wide column band of tiles.
    const int wg = blockIdx.x;
    const int xcd = wg & 7;
    const int i = wg >> 3;
    const int nt = xcd * NB + (i % NB);
    const int mt = i / NB;
    const int m0 = mt * 256;
    const int n0 = nt * 256;

    const int tid = threadIdx.x;
    const int lane = tid & 63;
    const int wave = tid >> 6;            // 0..7
    const int wr = wave >> 2;             // 0..1 (M)
    const int wc = wave & 3;              // 0..3 (N)
    const int q = lane >> 4;              // 0..3
    const int rr = lane & 7;

    // ds_read addressing (bytes within a 16 KB unit region)
    const uint32_t cb0 = (uint32_t)((q ^ rr) << 4);         // ks=0
    const uint32_t cb1 = (uint32_t)(((4 + q) ^ rr) << 4);   // ks=1
    const uint32_t baseA = (uint32_t)((wr * 64 + (lane & 15)) * 128);
    const uint32_t baseB = (uint32_t)((wc * 32 + (lane & 15)) * 128);

    // staging source addressing
    const uint32_t scb = (uint32_t)((((lane & 7) ^ ((lane >> 3) & 7))) << 4);
    const int lr = lane >> 3;             // 0..7
    const size_t K2 = (size_t)K * 2;
    size_t aOff[2][2], bOff[2][2];
#pragma unroll
    for (int ii = 0; ii < 2; ++ii)
#pragma unroll
        for (int h = 0; h < 2; ++h) {
            int gA = m0 + wave * 8 + lr + ii * 128 + h * 64;
            int gB = n0 + ((wave >> 2) + 2 * ii) * 64 + h * 32 + (wave & 3) * 8 + lr;
            aOff[ii][h] = (size_t)gA * K2 + scb;
            bOff[ii][h] = (size_t)gB * K2 + scb;
        }
    const char* Ab = (const char*)A;
    const char* Bb = (const char*)Bt;

    f32x4 acc[8][4];
#pragma unroll
    for (int m = 0; m < 8; ++m)
#pragma unroll
        for (int n = 0; n < 4; ++n) acc[m][n] = (f32x4){0.f, 0.f, 0.f, 0.f};

    const int nk = K / 64;

    // Prologue: stage tiles 0 and 1, unit order Ae,Be,Bo,Ao per tile.
    STG_A(0, 0); STG_B(0, 0); STG_B(0, 1); STG_A(0, 1);
    STG_A(1, 0); STG_B(1, 0); STG_B(1, 1); STG_A(1, 1);
    VM(12);                               // tile0 Ae,Be complete; 6 units in flight
    wg_barrier();

    bf16x8 a0[4][2], a1[4][2];
    bf16x8 b0[2][2], b1[2][2];

    for (int kt = 0; kt < nk; ++kt) {
        const int c = kt & 1;
        const char* A0r = ldsA + c * 32768;
        const char* A1r = A0r + 16384;
        const char* B0r = ldsB + c * 32768;
        const char* B1r = B0r + 16384;
        // ---- P1
        RD_A0
        RD_B0
        if (kt + 1 < nk) { VM(10); } else { VM(2); }
        wg_barrier();
        MQ(a0, b0, 0, 0)
        LGKM0;                 // P1 reads of Ae/Be done before P2 can overwrite
        wg_barrier();
        // ---- P2
        RD_B1
        STG_A(kt + 2, 0); STG_B(kt + 2, 0);
        if (kt + 2 < nk) { VM(12); } else if (kt + 1 < nk) { VM(8); } else { VM(0); }
        wg_barrier();
        MQ(a0, b1, 0, 2)
        LGKM0;                 // P2 reads of Bo done before P3 can overwrite
        wg_barrier();
        // ---- P3
        RD_A1
        STG_B(kt + 2, 1);
        wg_barrier();
        MQ(a1, b0, 4, 0)
        LGKM0;                 // P3 reads of Ao done before P4 can overwrite
        wg_barrier();
        // ---- P4
        STG_A(kt + 2, 1);
        if (kt + 2 < nk) {
            VM(12);
            wg_barrier();
        } else if (kt + 1 < nk) {
            VM(4);
            wg_barrier();
        }
        MQ(a1, b1, 4, 2)
        // no trailing barrier: P4 has no ds_reads; P1(t+1)'s reads target the
        // other parity, whose writes were drained at this phase's VM+barrier.
    }

    // Epilogue. Row/col mapping follows the interleaved unit layout:
    //   rows:  m0 + wr*128 + (mi>>2)*64 + (mi&3)*16 + q*4 + j
    //   cols:  n0 + wc*64  + (ni>>1)*32 + (ni&1)*16 + (lane&15)
#pragma unroll
    for (int mi = 0; mi < 8; ++mi) {
#pragma unroll
        for (int ni = 0; ni < 4; ++ni) {
            const int col = n0 + wc * 64 + (ni >> 1) * 32 + (ni & 1) * 16 + (lane & 15);
            const float bc = bias[col];
#pragma unroll
            for (int j = 0; j < 4; ++j) {
                const int row = m0 + wr * 128 + (mi >> 2) * 64 + (mi & 3) * 16 + q * 4 + j;
                float v = acc[mi][ni][j] + bc;
                if (MODE == 1) {
                    // tanh-form GELU via fast exp (max dev vs erf-GELU ~3e-4)
                    float u = 1.5957691216057308f * (v + 0.044715f * v * v * v);
                    float s = 1.0f / (1.0f + __expf(-u));
                    outh[(size_t)row * N + col] = __float2bfloat16(v * s);
                } else {
                    outf[(size_t)row * N + col] =
                        x[(size_t)row * N + col] * g_res[row] + v * g_post[row];
                }
            }
        }
    }
}

// ---------------------------------------------------------------------------
// Workspace layout (~235.2 MB): W1T, W2T, Abuf, Hbuf, Wfold, gres, gpost
// ---------------------------------------------------------------------------
extern "C" void kernel_launch(void* const* d_in, const int* in_sizes, int n_in,
                              void* d_out, int out_size, void* d_ws, size_t ws_size,
                              hipStream_t stream) {
    const float* x          = (const float*)d_in[0];
    const float* phi_pre_w  = (const float*)d_in[1];
    const float* phi_pre_b  = (const float*)d_in[2];
    const float* phi_post_w = (const float*)d_in[3];
    const float* phi_post_b = (const float*)d_in[4];
    const float* phi_res_w  = (const float*)d_in[5];
    const float* phi_res_b  = (const float*)d_in[6];
    const float* alpha_pre  = (const float*)d_in[7];
    const float* alpha_post = (const float*)d_in[8];
    const float* alpha_res  = (const float*)d_in[9];
    const float* b_pre      = (const float*)d_in[10];
    const float* b_post     = (const float*)d_in[11];
    const float* b_res      = (const float*)d_in[12];
    const float* W1         = (const float*)d_in[13];
    const float* b1         = (const float*)d_in[14];
    const float* W2         = (const float*)d_in[15];
    const float* b2         = (const float*)d_in[16];
    float* out = (float*)d_out;

    char* ws = (char*)d_ws;
    __hip_bfloat16* W1T  = (__hip_bfloat16*)ws;                      // [DFF][DIM]
    __hip_bfloat16* W2T  = W1T + (size_t)DFF * DIM;                  // [DIM][DFF]
    __hip_bfloat16* Abuf = W2T + (size_t)DIM * DFF;                  // [NROWS][DIM]
    __hip_bfloat16* Hbuf = Abuf + (size_t)NROWS * DIM;               // [NROWS][DFF]
    float* Wfold = (float*)(Hbuf + (size_t)NROWS * DFF);             // [24][DIM]
    float* gres  = Wfold + NFOLD * DIM;
    float* gpost = gres + NROWS;

    fold_kernel<<<(NFOLD * DIM + 255) / 256, 256, 0, stream>>>(phi_pre_w, phi_post_w,
                                                               phi_res_w, Wfold);
    transpose_to_bf16<<<dim3(DFF / 32, DIM / 32), 256, 0, stream>>>(W1, W1T, DIM, DFF);
    transpose_to_bf16<<<dim3(DIM / 32, DFF / 32), 256, 0, stream>>>(W2, W2T, DFF, DIM);
    gating_kernel<<<NROWS / 8, 512, 0, stream>>>(x, Wfold, phi_pre_b, phi_post_b, phi_res_b,
                                                 alpha_pre, alpha_post, alpha_res,
                                                 b_pre, b_post, b_res, Abuf, gres, gpost);
    // GEMM1: [8192 x 2048] @ W1 -> gelu -> Hbuf [8192 x 8192]; grid 32x32=1024, NB=4
    gemm256<1, 4><<<1024, 512, 0, stream>>>(
        Abuf, W1T, NROWS, DFF, DIM, b1, Hbuf, nullptr, nullptr, nullptr, nullptr);
    // GEMM2: [8192 x 8192] @ W2 -> out [8192 x 2048]; grid 32x8=256, NB=1
    gemm256<2, 1><<<256, 512, 0, stream>>>(
        Hbuf, W2T, NROWS, DIM, DFF, b2, nullptr, out, x, gres, gpost);
}

// Round 7
// 690.327 us; speedup vs baseline: 1.6156x; 1.0446x over previous
//
#include <hip/hip_runtime.h>
#include <hip/hip_bf16.h>
#include <cstdint>
#include <cstddef>

// Problem constants (B=4, T=2048, DIM=2048, S=4, DFF=8192)
#define DIM   2048
#define DFF   8192
#define NROWS 8192   // B*T
#define NFOLD 24     // 4 (pre) + 4 (post) + 16 (res)

typedef float f32x4 __attribute__((ext_vector_type(4)));
typedef __bf16 bf16x8 __attribute__((ext_vector_type(8)));

__device__ __forceinline__ float sigmoidf_(float v) { return 1.0f / (1.0f + expf(-v)); }

__device__ __forceinline__ unsigned short f2bf(float v) {
    union { __hip_bfloat16 h; unsigned short u; } cv;
    cv.h = __float2bfloat16(v);
    return cv.u;
}

__device__ __forceinline__ void async_copy16(const void* g, void* l) {
    __builtin_amdgcn_global_load_lds((const __attribute__((address_space(1))) void*)g,
                                     (__attribute__((address_space(3))) void*)l, 16, 0, 0);
}

// Raw workgroup barrier WITHOUT waitcnt drain (keeps global_load_lds in flight).
__device__ __forceinline__ void wg_barrier() {
    asm volatile("" ::: "memory");
    __builtin_amdgcn_s_barrier();
    asm volatile("" ::: "memory");
}

#define VM(n) asm volatile("s_waitcnt vmcnt(" #n ")" ::: "memory")
// Force this wave's ds_reads to COMPLETE before crossing the phase-closing
// barrier (round-4 lesson: compiler may sink consuming MFMAs past the barrier,
// so read completion must be pinned by the lgkm counter, not by MFMA deps).
#define LGKM0 asm volatile("s_waitcnt lgkmcnt(0)" ::: "memory")

// ---------------------------------------------------------------------------
// Fold phi weights: Wfold[r][d] = sum_{j<4} src[r][j*DIM + d], r in [0,24)
// ---------------------------------------------------------------------------
__global__ __launch_bounds__(256) void fold_kernel(const float* __restrict__ pre_w,
                                                   const float* __restrict__ post_w,
                                                   const float* __restrict__ res_w,
                                                   float* __restrict__ Wfold) {
    int idx = blockIdx.x * 256 + threadIdx.x;
    if (idx >= NFOLD * DIM) return;
    int r = idx >> 11;          // /DIM
    int d = idx & (DIM - 1);
    const float* src;
    if (r < 4)      src = pre_w  + (size_t)r * (4 * DIM);
    else if (r < 8) src = post_w + (size_t)(r - 4) * (4 * DIM);
    else            src = res_w  + (size_t)(r - 8) * (4 * DIM);
    Wfold[idx] = src[d] + src[DIM + d] + src[2 * DIM + d] + src[3 * DIM + d];
}

// ---------------------------------------------------------------------------
// Transpose f32 [R][C] -> bf16 [C][R]
// ---------------------------------------------------------------------------
__global__ __launch_bounds__(256) void transpose_to_bf16(const float* __restrict__ in,
                                                         __hip_bfloat16* __restrict__ out,
                                                         int R, int C) {
    __shared__ float tile[32][33];
    int bx = blockIdx.x, by = blockIdx.y;
    int tx = threadIdx.x & 31, ty0 = threadIdx.x >> 5;
#pragma unroll
    for (int i = 0; i < 4; i++) {
        int ty = ty0 + i * 8;
        tile[ty][tx] = in[(size_t)(by * 32 + ty) * C + bx * 32 + tx];
    }
    __syncthreads();
#pragma unroll
    for (int i = 0; i < 4; i++) {
        int ty = ty0 + i * 8;
        out[(size_t)(bx * 32 + ty) * R + by * 32 + tx] = __float2bfloat16(tile[tx][ty]);
    }
}

// ---------------------------------------------------------------------------
// Gating: wave-per-row, 8 rows per block (512 threads).
// ---------------------------------------------------------------------------
__global__ __launch_bounds__(512) void gating_kernel(
    const float* __restrict__ x, const float* __restrict__ Wfold,
    const float* __restrict__ phi_pre_b, const float* __restrict__ phi_post_b,
    const float* __restrict__ phi_res_b,
    const float* __restrict__ alpha_pre, const float* __restrict__ alpha_post,
    const float* __restrict__ alpha_res,
    const float* __restrict__ b_pre, const float* __restrict__ b_post,
    const float* __restrict__ b_res,
    __hip_bfloat16* __restrict__ Abuf,
    float* __restrict__ g_res_arr, float* __restrict__ g_post_arr) {
    const int tid = threadIdx.x;
    const int lane = tid & 63, wave = tid >> 6;
    const int row = blockIdx.x * 8 + wave;

    const float4* x4 = (const float4*)x + (size_t)row * 512;
    const float4* w4 = (const float4*)Wfold;

    float4 xv[8];
#pragma unroll
    for (int j = 0; j < 8; j++) xv[j] = x4[j * 64 + lane];

    float p[25];
    p[24] = 0.f;
#pragma unroll
    for (int j = 0; j < 8; j++)
        p[24] += xv[j].x * xv[j].x + xv[j].y * xv[j].y + xv[j].z * xv[j].z + xv[j].w * xv[j].w;

    for (int r = 0; r < NFOLD; r++) {
        float acc = 0.f;
#pragma unroll
        for (int j = 0; j < 8; j++) {
            float4 wv = w4[r * 512 + j * 64 + lane];
            acc += xv[j].x * wv.x + xv[j].y * wv.y + xv[j].z * wv.z + xv[j].w * wv.w;
        }
        p[r] = acc;
    }

#pragma unroll
    for (int r = 0; r < 25; r++) {
        float v = p[r];
#pragma unroll
        for (int off = 1; off < 64; off <<= 1) v += __shfl_xor(v, off, 64);
        p[r] = v;
    }

    const float rms = rsqrtf(p[24] / (float)DIM + 1.1920928955078125e-07f);
    const float ap = alpha_pre[0], aq = alpha_post[0], ar = alpha_res[0];
    float gpre = 0.f, gpost = 0.f;
#pragma unroll
    for (int s = 0; s < 4; s++) {
        gpre  += sigmoidf_(ap * (rms * p[s]     + phi_pre_b[s])  + b_pre[s]);
        gpost += 2.0f * sigmoidf_(aq * (rms * p[4 + s] + phi_post_b[s]) + b_post[s]);
    }
    float Mm[4][4];
#pragma unroll
    for (int i = 0; i < 4; i++)
#pragma unroll
        for (int j = 0; j < 4; j++) {
            int k = i * 4 + j;
            Mm[i][j] = expf(ar * (rms * p[8 + k] + phi_res_b[k]) + b_res[k]);
        }
    for (int it = 0; it < 10; ++it) {
#pragma unroll
        for (int i = 0; i < 4; i++) {
            float rs = 1.0f / (Mm[i][0] + Mm[i][1] + Mm[i][2] + Mm[i][3]);
#pragma unroll
            for (int j = 0; j < 4; j++) Mm[i][j] *= rs;
        }
#pragma unroll
        for (int j = 0; j < 4; j++) {
            float cs = 1.0f / (Mm[0][j] + Mm[1][j] + Mm[2][j] + Mm[3][j]);
#pragma unroll
            for (int i = 0; i < 4; i++) Mm[i][j] *= cs;
        }
    }
    float gres = 0.f;
#pragma unroll
    for (int i = 0; i < 4; i++)
#pragma unroll
        for (int j = 0; j < 4; j++) gres += Mm[i][j];

    __hip_bfloat16* arow = Abuf + (size_t)row * DIM;
#pragma unroll
    for (int j = 0; j < 8; j++) {
        ushort4 u;
        u.x = f2bf(xv[j].x * gpre); u.y = f2bf(xv[j].y * gpre);
        u.z = f2bf(xv[j].z * gpre); u.w = f2bf(xv[j].w * gpre);
        *reinterpret_cast<ushort4*>(arow + (j * 64 + lane) * 4) = u;
    }
    if (lane == 0) {
        g_res_arr[row]  = gres;
        g_post_arr[row] = gpost;
    }
}

// ---------------------------------------------------------------------------
// 256x256 bf16 GEMM. 4 balanced phases per K-tile; 4/8/8/4 ds_reads per
// phase, each read exactly ONE phase before its consuming MFMA; ONE barrier
// per phase; counted vmcnt; XOR-swizzled LDS.
//   C[M][N] = A[M][K] @ Bt[N][K]^T; 8 waves (2M x 4N); per-wave out 128x64;
//   BK=64; LDS 128 KiB = 2 parities x {A0,A1,B0,B1} 16 KB units.
// Units (read-aligned interleaves):
//   A0: rows {0-63,128-191}   (mh=0) [a0] | A1: rows {64-127,192-255} [a1]
//   B0: cols {0-31,64-95,128-159,192-223} [b0] | B1: +32 [b1]
// Unit region [128 rows][128 B], byte col ^ ((row&7)<<4); global_load_lds
// writes linearly, inverse XOR pre-applied on the per-lane global source.
//
// Phase p of tile t = { ds_reads(for p+1's MFMA); stage one unit of t+2;
//                       16 MFMA; LGKM0; VM(N); s_barrier }
//   P1: rd b1(t)  [4]; stg A0(t+2); MFMA(a0,b0); VM(12)
//   P2: rd a1(t)  [8]; stg B0(t+2); MFMA(a0,b1); VM(10) [drains A0(t+1)]
//   P3: rd a0(t+1)[8]; stg A1(t+2); MFMA(a1,b0); VM(10) [drains B0(t+1)]
//   P4: rd b0(t+1)[4]; stg B1(t+2); MFMA(a1,b1); VM(8)  [drains A1,B1(t+1)]
// Steady-state FIFO audit: after P4(t-1) VM(8), outstanding =
// {A0,B0,A1,B1}(t+1) = 8 loads; each phase issues 2 and drains per above.
// Region overwrite safety: every unit's stage lands >=2 barriers after that
// unit's last LGKM0-pinned reads.
// PROLOGUE FIX (round 6 post-mortem): tile-0 fragment reads must be pinned by
// LGKM0 + barrier BEFORE the loop, because P1(kt=0) immediately stages
// A0(tile2) into the same parity-0 region those reads consume.
// Tail: kt >= nk-2 uses VM(0) everywhere (stages already stopped).
// ---------------------------------------------------------------------------
#define RD_A(DST, REG)                                                            \
    _Pragma("unroll") for (int m = 0; m < 4; ++m) {                               \
        DST[m][0] = *(const bf16x8*)((REG) + baseA + m * 2048 + cb0);             \
        DST[m][1] = *(const bf16x8*)((REG) + baseA + m * 2048 + cb1);             \
    }
#define RD_B(DST, REG)                                                            \
    _Pragma("unroll") for (int n = 0; n < 2; ++n) {                               \
        DST[n][0] = *(const bf16x8*)((REG) + baseB + n * 2048 + cb0);             \
        DST[n][1] = *(const bf16x8*)((REG) + baseB + n * 2048 + cb1);             \
    }

#define MQ(AF, BF, MO, NO)                                                        \
    __builtin_amdgcn_s_setprio(1);                                                \
    _Pragma("unroll") for (int m = 0; m < 4; ++m)                                 \
    _Pragma("unroll") for (int n = 0; n < 2; ++n) {                               \
        acc[(MO) + m][(NO) + n] = __builtin_amdgcn_mfma_f32_16x16x32_bf16(        \
            AF[m][0], BF[n][0], acc[(MO) + m][(NO) + n], 0, 0, 0);                \
        acc[(MO) + m][(NO) + n] = __builtin_amdgcn_mfma_f32_16x16x32_bf16(        \
            AF[m][1], BF[n][1], acc[(MO) + m][(NO) + n], 0, 0, 0);                \
    }                                                                             \
    __builtin_amdgcn_s_setprio(0);

#define STG_A(t_, h_)                                                             \
    if ((t_) < nk) {                                                              \
        char* l_ = ldsA + (((t_) & 1) * 32768) + (h_) * 16384 + wave * 1024;      \
        async_copy16(Ab + aOff[0][h_] + (size_t)(t_) * 128, l_);                  \
        async_copy16(Ab + aOff[1][h_] + (size_t)(t_) * 128, l_ + 8192);           \
    }
#define STG_B(t_, h_)                                                             \
    if ((t_) < nk) {                                                              \
        char* l_ = ldsB + (((t_) & 1) * 32768) + (h_) * 16384 + wave * 1024;      \
        async_copy16(Bb + bOff[0][h_] + (size_t)(t_) * 128, l_);                  \
        async_copy16(Bb + bOff[1][h_] + (size_t)(t_) * 128, l_ + 8192);           \
    }

template <int MODE, int NB>
__global__ __launch_bounds__(512, 2) void gemm256(
    const __hip_bfloat16* __restrict__ A, const __hip_bfloat16* __restrict__ Bt,
    int M, int N, int K, const float* __restrict__ bias,
    __hip_bfloat16* __restrict__ outh, float* __restrict__ outf,
    const float* __restrict__ x, const float* __restrict__ g_res,
    const float* __restrict__ g_post) {
    __shared__ __align__(16) char ldsA[65536];
    __shared__ __align__(16) char ldsB[65536];

    // XCD band swizzle: each XCD owns an NB-wide column band of tiles.
    const int wg = blockIdx.x;
    const int xcd = wg & 7;
    const int i = wg >> 3;
    const int nt = xcd * NB + (i % NB);
    const int mt = i / NB;
    const int m0 = mt * 256;
    const int n0 = nt * 256;

    const int tid = threadIdx.x;
    const int lane = tid & 63;
    const int wave = tid >> 6;            // 0..7
    const int wr = wave >> 2;             // 0..1 (M)
    const int wc = wave & 3;              // 0..3 (N)
    const int q = lane >> 4;              // 0..3
    const int rr = lane & 7;

    // ds_read addressing (bytes within a 16 KB unit region)
    const uint32_t cb0 = (uint32_t)((q ^ rr) << 4);         // ks=0
    const uint32_t cb1 = (uint32_t)(((4 + q) ^ rr) << 4);   // ks=1
    const uint32_t baseA = (uint32_t)((wr * 64 + (lane & 15)) * 128);
    const uint32_t baseB = (uint32_t)((wc * 32 + (lane & 15)) * 128);

    // staging source addressing
    const uint32_t scb = (uint32_t)((((lane & 7) ^ ((lane >> 3) & 7))) << 4);
    const int lr = lane >> 3;             // 0..7
    const size_t K2 = (size_t)K * 2;
    size_t aOff[2][2], bOff[2][2];
#pragma unroll
    for (int ii = 0; ii < 2; ++ii)
#pragma unroll
        for (int h = 0; h < 2; ++h) {
            int gA = m0 + wave * 8 + lr + ii * 128 + h * 64;
            int gB = n0 + ((wave >> 2) + 2 * ii) * 64 + h * 32 + (wave & 3) * 8 + lr;
            aOff[ii][h] = (size_t)gA * K2 + scb;
            bOff[ii][h] = (size_t)gB * K2 + scb;
        }
    const char* Ab = (const char*)A;
    const char* Bb = (const char*)Bt;

    f32x4 acc[8][4];
#pragma unroll
    for (int m = 0; m < 8; ++m)
#pragma unroll
        for (int n = 0; n < 4; ++n) acc[m][n] = (f32x4){0.f, 0.f, 0.f, 0.f};

    const int nk = K / 64;

    // Prologue: stage tiles 0 and 1 (unit order A0,B0,A1,B1 per tile);
    // drain tile 0; read a0(0), b0(0); PIN those reads before the loop.
    STG_A(0, 0); STG_B(0, 0); STG_A(0, 1); STG_B(0, 1);
    STG_A(1, 0); STG_B(1, 0); STG_A(1, 1); STG_B(1, 1);
    VM(8);
    wg_barrier();

    bf16x8 a0[4][2], a1[4][2];
    bf16x8 b0[2][2], b1[2][2];
    RD_A(a0, ldsA)
    RD_B(b0, ldsB)
    LGKM0;          // PROLOGUE FIX: tile-0 A0/B0 reads complete in all waves
    wg_barrier();   // before P1(kt=0) stages A0(tile2) into the same region

    for (int kt = 0; kt < nk; ++kt) {
        const int c = kt & 1;
        const int cn = c ^ 1;
        const char* Ac = ldsA + c * 32768;
        const char* Bc = ldsB + c * 32768;
        const char* An = ldsA + cn * 32768;
        const char* Bn = ldsB + cn * 32768;
        const bool steady = (kt < nk - 2);
        // ---- P1: rd b1(t); stage A0(t+2); MFMA(a0,b0)
        RD_B(b1, Bc + 16384)
        STG_A(kt + 2, 0)
        MQ(a0, b0, 0, 0)
        LGKM0;
        if (steady) { VM(12); } else { VM(0); }
        wg_barrier();
        // ---- P2: rd a1(t); stage B0(t+2); MFMA(a0,b1)
        RD_A(a1, Ac + 16384)
        STG_B(kt + 2, 0)
        MQ(a0, b1, 0, 2)
        LGKM0;
        if (steady) { VM(10); } else { VM(0); }
        wg_barrier();
        // ---- P3: rd a0(t+1); stage A1(t+2); MFMA(a1,b0)
        if (kt + 1 < nk) { RD_A(a0, An) }
        STG_A(kt + 2, 1)
        MQ(a1, b0, 4, 0)
        LGKM0;
        if (steady) { VM(10); } else { VM(0); }
        wg_barrier();
        // ---- P4: rd b0(t+1); stage B1(t+2); MFMA(a1,b1)
        if (kt + 1 < nk) { RD_B(b0, Bn) }
        STG_B(kt + 2, 1)
        MQ(a1, b1, 4, 2)
        LGKM0;
        if (steady) { VM(8); } else { VM(0); }
        wg_barrier();
    }

    // Epilogue. Row/col mapping follows the interleaved unit layout:
    //   rows:  m0 + wr*128 + (mi>>2)*64 + (mi&3)*16 + q*4 + j
    //   cols:  n0 + wc*64  + (ni>>1)*32 + (ni&1)*16 + (lane&15)
#pragma unroll
    for (int mi = 0; mi < 8; ++mi) {
#pragma unroll
        for (int ni = 0; ni < 4; ++ni) {
            const int col = n0 + wc * 64 + (ni >> 1) * 32 + (ni & 1) * 16 + (lane & 15);
            const float bc = bias[col];
#pragma unroll
            for (int j = 0; j < 4; ++j) {
                const int row = m0 + wr * 128 + (mi >> 2) * 64 + (mi & 3) * 16 + q * 4 + j;
                float v = acc[mi][ni][j] + bc;
                if (MODE == 1) {
                    // tanh-form GELU via fast exp (max dev vs erf-GELU ~3e-4)
                    float u = 1.5957691216057308f * (v + 0.044715f * v * v * v);
                    float s = 1.0f / (1.0f + __expf(-u));
                    outh[(size_t)row * N + col] = __float2bfloat16(v * s);
                } else {
                    outf[(size_t)row * N + col] =
                        x[(size_t)row * N + col] * g_res[row] + v * g_post[row];
                }
            }
        }
    }
}

// ---------------------------------------------------------------------------
// Workspace layout (~235.2 MB): W1T, W2T, Abuf, Hbuf, Wfold, gres, gpost
// ---------------------------------------------------------------------------
extern "C" void kernel_launch(void* const* d_in, const int* in_sizes, int n_in,
                              void* d_out, int out_size, void* d_ws, size_t ws_size,
                              hipStream_t stream) {
    const float* x          = (const float*)d_in[0];
    const float* phi_pre_w  = (const float*)d_in[1];
    const float* phi_pre_b  = (const float*)d_in[2];
    const float* phi_post_w = (const float*)d_in[3];
    const float* phi_post_b = (const float*)d_in[4];
    const float* phi_res_w  = (const float*)d_in[5];
    const float* phi_res_b  = (const float*)d_in[6];
    const float* alpha_pre  = (const float*)d_in[7];
    const float* alpha_post = (const float*)d_in[8];
    const float* alpha_res  = (const float*)d_in[9];
    const float* b_pre      = (const float*)d_in[10];
    const float* b_post     = (const float*)d_in[11];
    const float* b_res      = (const float*)d_in[12];
    const float* W1         = (const float*)d_in[13];
    const float* b1         = (const float*)d_in[14];
    const float* W2         = (const float*)d_in[15];
    const float* b2         = (const float*)d_in[16];
    float* out = (float*)d_out;

    char* ws = (char*)d_ws;
    __hip_bfloat16* W1T  = (__hip_bfloat16*)ws;                      // [DFF][DIM]
    __hip_bfloat16* W2T  = W1T + (size_t)DFF * DIM;                  // [DIM][DFF]
    __hip_bfloat16* Abuf = W2T + (size_t)DIM * DFF;                  // [NROWS][DIM]
    __hip_bfloat16* Hbuf = Abuf + (size_t)NROWS * DIM;               // [NROWS][DFF]
    float* Wfold = (float*)(Hbuf + (size_t)NROWS * DFF);             // [24][DIM]
    float* gres  = Wfold + NFOLD * DIM;
    float* gpost = gres + NROWS;

    fold_kernel<<<(NFOLD * DIM + 255) / 256, 256, 0, stream>>>(phi_pre_w, phi_post_w,
                                                               phi_res_w, Wfold);
    transpose_to_bf16<<<dim3(DFF / 32, DIM / 32), 256, 0, stream>>>(W1, W1T, DIM, DFF);
    transpose_to_bf16<<<dim3(DIM / 32, DFF / 32), 256, 0, stream>>>(W2, W2T, DFF, DIM);
    gating_kernel<<<NROWS / 8, 512, 0, stream>>>(x, Wfold, phi_pre_b, phi_post_b, phi_res_b,
                                                 alpha_pre, alpha_post, alpha_res,
                                                 b_pre, b_post, b_res, Abuf, gres, gpost);
    // GEMM1: [8192 x 2048] @ W1 -> gelu -> Hbuf [8192 x 8192]; grid 32x32=1024, NB=4
    gemm256<1, 4><<<1024, 512, 0, stream>>>(
        Abuf, W1T, NROWS, DFF, DIM, b1, Hbuf, nullptr, nullptr, nullptr, nullptr);
    // GEMM2: [8192 x 8192] @ W2 -> out [8192 x 2048]; grid 32x8=256, NB=1
    gemm256<2, 1><<<256, 512, 0, stream>>>(
        Hbuf, W2T, NROWS, DIM, DFF, b2, nullptr, out, x, gres, gpost);
}

// Round 8
// 651.061 us; speedup vs baseline: 1.7130x; 1.0603x over previous
//
#include <hip/hip_runtime.h>
#include <hip/hip_bf16.h>
#include <cstdint>
#include <cstddef>

// Problem constants (B=4, T=2048, DIM=2048, S=4, DFF=8192)
#define DIM   2048
#define DFF   8192
#define NROWS 8192   // B*T
#define NFOLD 24     // 4 (pre) + 4 (post) + 16 (res)

typedef float f32x4 __attribute__((ext_vector_type(4)));
typedef __bf16 bf16x8 __attribute__((ext_vector_type(8)));

__device__ __forceinline__ float sigmoidf_(float v) { return 1.0f / (1.0f + expf(-v)); }

__device__ __forceinline__ unsigned short f2bf(float v) {
    union { __hip_bfloat16 h; unsigned short u; } cv;
    cv.h = __float2bfloat16(v);
    return cv.u;
}

__device__ __forceinline__ void async_copy16(const void* g, void* l) {
    __builtin_amdgcn_global_load_lds((const __attribute__((address_space(1))) void*)g,
                                     (__attribute__((address_space(3))) void*)l, 16, 0, 0);
}

// Raw workgroup barrier WITHOUT waitcnt drain (keeps global_load_lds in flight).
__device__ __forceinline__ void wg_barrier() {
    asm volatile("" ::: "memory");
    __builtin_amdgcn_s_barrier();
    asm volatile("" ::: "memory");
}

#define VM(n)  asm volatile("s_waitcnt vmcnt(" #n ")" ::: "memory")
#define LGKM0  asm volatile("s_waitcnt lgkmcnt(0)" ::: "memory")
#define LGKM8  asm volatile("s_waitcnt lgkmcnt(8)" ::: "memory")
// rule #18: MFMA (register-only) can be hoisted past inline-asm lgkmcnt by the
// scheduler; pin with a full sched_barrier immediately after the wait.
#define SCHED0 __builtin_amdgcn_sched_barrier(0)

// ---------------------------------------------------------------------------
// Fold phi weights: Wfold[r][d] = sum_{j<4} src[r][j*DIM + d], r in [0,24)
// ---------------------------------------------------------------------------
__global__ __launch_bounds__(256) void fold_kernel(const float* __restrict__ pre_w,
                                                   const float* __restrict__ post_w,
                                                   const float* __restrict__ res_w,
                                                   float* __restrict__ Wfold) {
    int idx = blockIdx.x * 256 + threadIdx.x;
    if (idx >= NFOLD * DIM) return;
    int r = idx >> 11;          // /DIM
    int d = idx & (DIM - 1);
    const float* src;
    if (r < 4)      src = pre_w  + (size_t)r * (4 * DIM);
    else if (r < 8) src = post_w + (size_t)(r - 4) * (4 * DIM);
    else            src = res_w  + (size_t)(r - 8) * (4 * DIM);
    Wfold[idx] = src[d] + src[DIM + d] + src[2 * DIM + d] + src[3 * DIM + d];
}

// ---------------------------------------------------------------------------
// Transpose f32 [R][C] -> bf16 [C][R]
// ---------------------------------------------------------------------------
__global__ __launch_bounds__(256) void transpose_to_bf16(const float* __restrict__ in,
                                                         __hip_bfloat16* __restrict__ out,
                                                         int R, int C) {
    __shared__ float tile[32][33];
    int bx = blockIdx.x, by = blockIdx.y;
    int tx = threadIdx.x & 31, ty0 = threadIdx.x >> 5;
#pragma unroll
    for (int i = 0; i < 4; i++) {
        int ty = ty0 + i * 8;
        tile[ty][tx] = in[(size_t)(by * 32 + ty) * C + bx * 32 + tx];
    }
    __syncthreads();
#pragma unroll
    for (int i = 0; i < 4; i++) {
        int ty = ty0 + i * 8;
        out[(size_t)(bx * 32 + ty) * R + by * 32 + tx] = __float2bfloat16(tile[tx][ty]);
    }
}

// ---------------------------------------------------------------------------
// Gating: wave-per-row, 8 rows per block (512 threads).
// ---------------------------------------------------------------------------
__global__ __launch_bounds__(512) void gating_kernel(
    const float* __restrict__ x, const float* __restrict__ Wfold,
    const float* __restrict__ phi_pre_b, const float* __restrict__ phi_post_b,
    const float* __restrict__ phi_res_b,
    const float* __restrict__ alpha_pre, const float* __restrict__ alpha_post,
    const float* __restrict__ alpha_res,
    const float* __restrict__ b_pre, const float* __restrict__ b_post,
    const float* __restrict__ b_res,
    __hip_bfloat16* __restrict__ Abuf,
    float* __restrict__ g_res_arr, float* __restrict__ g_post_arr) {
    const int tid = threadIdx.x;
    const int lane = tid & 63, wave = tid >> 6;
    const int row = blockIdx.x * 8 + wave;

    const float4* x4 = (const float4*)x + (size_t)row * 512;
    const float4* w4 = (const float4*)Wfold;

    float4 xv[8];
#pragma unroll
    for (int j = 0; j < 8; j++) xv[j] = x4[j * 64 + lane];

    float p[25];
    p[24] = 0.f;
#pragma unroll
    for (int j = 0; j < 8; j++)
        p[24] += xv[j].x * xv[j].x + xv[j].y * xv[j].y + xv[j].z * xv[j].z + xv[j].w * xv[j].w;

    for (int r = 0; r < NFOLD; r++) {
        float acc = 0.f;
#pragma unroll
        for (int j = 0; j < 8; j++) {
            float4 wv = w4[r * 512 + j * 64 + lane];
            acc += xv[j].x * wv.x + xv[j].y * wv.y + xv[j].z * wv.z + xv[j].w * wv.w;
        }
        p[r] = acc;
    }

#pragma unroll
    for (int r = 0; r < 25; r++) {
        float v = p[r];
#pragma unroll
        for (int off = 1; off < 64; off <<= 1) v += __shfl_xor(v, off, 64);
        p[r] = v;
    }

    const float rms = rsqrtf(p[24] / (float)DIM + 1.1920928955078125e-07f);
    const float ap = alpha_pre[0], aq = alpha_post[0], ar = alpha_res[0];
    float gpre = 0.f, gpost = 0.f;
#pragma unroll
    for (int s = 0; s < 4; s++) {
        gpre  += sigmoidf_(ap * (rms * p[s]     + phi_pre_b[s])  + b_pre[s]);
        gpost += 2.0f * sigmoidf_(aq * (rms * p[4 + s] + phi_post_b[s]) + b_post[s]);
    }
    float Mm[4][4];
#pragma unroll
    for (int i = 0; i < 4; i++)
#pragma unroll
        for (int j = 0; j < 4; j++) {
            int k = i * 4 + j;
            Mm[i][j] = expf(ar * (rms * p[8 + k] + phi_res_b[k]) + b_res[k]);
        }
    for (int it = 0; it < 10; ++it) {
#pragma unroll
        for (int i = 0; i < 4; i++) {
            float rs = 1.0f / (Mm[i][0] + Mm[i][1] + Mm[i][2] + Mm[i][3]);
#pragma unroll
            for (int j = 0; j < 4; j++) Mm[i][j] *= rs;
        }
#pragma unroll
        for (int j = 0; j < 4; j++) {
            float cs = 1.0f / (Mm[0][j] + Mm[1][j] + Mm[2][j] + Mm[3][j]);
#pragma unroll
            for (int i = 0; i < 4; i++) Mm[i][j] *= cs;
        }
    }
    float gres = 0.f;
#pragma unroll
    for (int i = 0; i < 4; i++)
#pragma unroll
        for (int j = 0; j < 4; j++) gres += Mm[i][j];

    __hip_bfloat16* arow = Abuf + (size_t)row * DIM;
#pragma unroll
    for (int j = 0; j < 8; j++) {
        ushort4 u;
        u.x = f2bf(xv[j].x * gpre); u.y = f2bf(xv[j].y * gpre);
        u.z = f2bf(xv[j].z * gpre); u.w = f2bf(xv[j].w * gpre);
        *reinterpret_cast<ushort4*>(arow + (j * 64 + lane) * 4) = u;
    }
    if (lane == 0) {
        g_res_arr[row]  = gres;
        g_post_arr[row] = gpost;
    }
}

// ---------------------------------------------------------------------------
// 256x256 bf16 GEMM — m201-discipline transcription.
//   C[M][N] = A[M][K] @ Bt[N][K]^T; 8 waves (2M x 4N); per-wave out 128x64;
//   BK=64; LDS 128 KiB = 2 parities x {A0,A1,B0,B1} 16 KB units.
// Units (read-aligned interleaves):
//   A0: rows {0-63,128-191} [a0] | A1: rows {64-127,192-255} [a1]
//   B0: cols {0-31,64-95,128-159,192-223} [b0] | B1: +32 [b1]
// Unit region [128 rows][128 B], byte col ^ ((row&7)<<4); global_load_lds
// writes linearly, inverse XOR pre-applied on the per-lane global source.
//
// Phase = { ds_reads (consumed THIS phase); 1 stage; [early lgkm drain];
//           barrier; lgkmcnt(0); sched_barrier; setprio1; 16 MFMA; setprio0;
//           barrier }        -- two barriers/phase, pure MFMA region.
//   P1: rd a0(t)[8]+b0(t)[4]; stg B1(t+1); lgkmcnt(8); || MFMA(a0,b0)
//   P2: rd b1(t)[4];          stg A0(t+2);             || MFMA(a0,b1)
//   P3: rd a1(t)[8];          stg B0(t+2);             || MFMA(a1,b0)
//   P4: (no reads);           stg A1(t+2); VM(6|0);    || MFMA(a1,b1)
// vmcnt ONCE per K-tile: VM(6) at P4 keeps 3 units in flight and drains
// exactly {A0,B0,A1,B1}(t+1) (FIFO audit: after VM(6)@P4(t-1) outstanding =
// A0,B0,A1(t+1); tile t issues B1(t+1),A0,B0,A1(t+2) -> 14 at P4(t); keep 6
// newest = tile t+2 units). Stage->read lead 5-7 phases; VM lead 3-6 phases.
// Overwrite safety: each stage targets a region whose last read was pinned by
// the PREVIOUS phase's lgkmcnt(0) (before that phase's MFMA < bar2 < stage).
// Tail: P4 uses VM(0) when t+2 >= nk; stage macros self-guard (t < nk).
// Prologue: stage tile0 {A0,B0,B1,A1} + tile1 {A0,B0,A1}; VM(6) drains tile0;
// B1(1) is staged by P1(t=0), completing the steady pattern.
// ---------------------------------------------------------------------------
#define RD_A(DST, REG)                                                            \
    _Pragma("unroll") for (int m = 0; m < 4; ++m) {                               \
        DST[m][0] = *(const bf16x8*)((REG) + baseA + m * 2048 + cb0);             \
        DST[m][1] = *(const bf16x8*)((REG) + baseA + m * 2048 + cb1);             \
    }
#define RD_B(DST, REG)                                                            \
    _Pragma("unroll") for (int n = 0; n < 2; ++n) {                               \
        DST[n][0] = *(const bf16x8*)((REG) + baseB + n * 2048 + cb0);             \
        DST[n][1] = *(const bf16x8*)((REG) + baseB + n * 2048 + cb1);             \
    }

#define MQ(AF, BF, MO, NO)                                                        \
    __builtin_amdgcn_s_setprio(1);                                                \
    _Pragma("unroll") for (int m = 0; m < 4; ++m)                                 \
    _Pragma("unroll") for (int n = 0; n < 2; ++n) {                               \
        acc[(MO) + m][(NO) + n] = __builtin_amdgcn_mfma_f32_16x16x32_bf16(        \
            AF[m][0], BF[n][0], acc[(MO) + m][(NO) + n], 0, 0, 0);                \
        acc[(MO) + m][(NO) + n] = __builtin_amdgcn_mfma_f32_16x16x32_bf16(        \
            AF[m][1], BF[n][1], acc[(MO) + m][(NO) + n], 0, 0, 0);                \
    }                                                                             \
    __builtin_amdgcn_s_setprio(0);

#define STG_A(t_, h_)                                                             \
    if ((t_) < nk) {                                                              \
        char* l_ = ldsA + (((t_) & 1) * 32768) + (h_) * 16384 + wave * 1024;      \
        async_copy16(Ab + aOff[0][h_] + (size_t)(t_) * 128, l_);                  \
        async_copy16(Ab + aOff[1][h_] + (size_t)(t_) * 128, l_ + 8192);           \
    }
#define STG_B(t_, h_)                                                             \
    if ((t_) < nk) {                                                              \
        char* l_ = ldsB + (((t_) & 1) * 32768) + (h_) * 16384 + wave * 1024;      \
        async_copy16(Bb + bOff[0][h_] + (size_t)(t_) * 128, l_);                  \
        async_copy16(Bb + bOff[1][h_] + (size_t)(t_) * 128, l_ + 8192);           \
    }

template <int MODE, int NB>
__global__ __launch_bounds__(512, 2) void gemm256(
    const __hip_bfloat16* __restrict__ A, const __hip_bfloat16* __restrict__ Bt,
    int M, int N, int K, const float* __restrict__ bias,
    __hip_bfloat16* __restrict__ outh, float* __restrict__ outf,
    const float* __restrict__ x, const float* __restrict__ g_res,
    const float* __restrict__ g_post) {
    __shared__ __align__(16) char ldsA[65536];
    __shared__ __align__(16) char ldsB[65536];

    // XCD band swizzle: each XCD owns an NB-wide column band of tiles.
    const int wg = blockIdx.x;
    const int xcd = wg & 7;
    const int i = wg >> 3;
    const int nt = xcd * NB + (i % NB);
    const int mt = i / NB;
    const int m0 = mt * 256;
    const int n0 = nt * 256;

    const int tid = threadIdx.x;
    const int lane = tid & 63;
    const int wave = tid >> 6;            // 0..7
    const int wr = wave >> 2;             // 0..1 (M)
    const int wc = wave & 3;              // 0..3 (N)
    const int q = lane >> 4;              // 0..3
    const int rr = lane & 7;

    // ds_read addressing (bytes within a 16 KB unit region)
    const uint32_t cb0 = (uint32_t)((q ^ rr) << 4);         // ks=0
    const uint32_t cb1 = (uint32_t)(((4 + q) ^ rr) << 4);   // ks=1
    const uint32_t baseA = (uint32_t)((wr * 64 + (lane & 15)) * 128);
    const uint32_t baseB = (uint32_t)((wc * 32 + (lane & 15)) * 128);

    // staging source addressing
    const uint32_t scb = (uint32_t)((((lane & 7) ^ ((lane >> 3) & 7))) << 4);
    const int lr = lane >> 3;             // 0..7
    const size_t K2 = (size_t)K * 2;
    size_t aOff[2][2], bOff[2][2];
#pragma unroll
    for (int ii = 0; ii < 2; ++ii)
#pragma unroll
        for (int h = 0; h < 2; ++h) {
            int gA = m0 + wave * 8 + lr + ii * 128 + h * 64;
            int gB = n0 + ((wave >> 2) + 2 * ii) * 64 + h * 32 + (wave & 3) * 8 + lr;
            aOff[ii][h] = (size_t)gA * K2 + scb;
            bOff[ii][h] = (size_t)gB * K2 + scb;
        }
    const char* Ab = (const char*)A;
    const char* Bb = (const char*)Bt;

    f32x4 acc[8][4];
#pragma unroll
    for (int m = 0; m < 8; ++m)
#pragma unroll
        for (int n = 0; n < 4; ++n) acc[m][n] = (f32x4){0.f, 0.f, 0.f, 0.f};

    const int nk = K / 64;

    // Prologue: tile0 {A0,B0,B1,A1} + tile1 {A0,B0,A1}; VM(6) = tile0 done.
    STG_A(0, 0); STG_B(0, 0); STG_B(0, 1); STG_A(0, 1);
    STG_A(1, 0); STG_B(1, 0); STG_A(1, 1);
    VM(6);
    wg_barrier();

    bf16x8 a0[4][2], a1[4][2];
    bf16x8 b0[2][2], b1[2][2];

    for (int kt = 0; kt < nk; ++kt) {
        const int c = kt & 1;
        const char* Ac = ldsA + c * 32768;
        const char* Bc = ldsB + c * 32768;
        // ---- P1: rd a0(t)+b0(t); stg B1(t+1); early lgkm drain
        RD_A(a0, Ac)
        RD_B(b0, Bc)
        STG_B(kt + 1, 1)
        LGKM8;
        wg_barrier();
        LGKM0; SCHED0;
        MQ(a0, b0, 0, 0)
        wg_barrier();
        // ---- P2: rd b1(t); stg A0(t+2)
        RD_B(b1, Bc + 16384)
        STG_A(kt + 2, 0)
        wg_barrier();
        LGKM0; SCHED0;
        MQ(a0, b1, 0, 2)
        wg_barrier();
        // ---- P3: rd a1(t); stg B0(t+2)
        RD_A(a1, Ac + 16384)
        STG_B(kt + 2, 0)
        wg_barrier();
        LGKM0; SCHED0;
        MQ(a1, b0, 4, 0)
        wg_barrier();
        // ---- P4: stg A1(t+2); single per-tile counted vmcnt
        STG_A(kt + 2, 1)
        if (kt + 2 < nk) { VM(6); } else { VM(0); }
        wg_barrier();
        MQ(a1, b1, 4, 2)
        wg_barrier();
    }

    // Epilogue. Row/col mapping follows the interleaved unit layout:
    //   rows:  m0 + wr*128 + (mi>>2)*64 + (mi&3)*16 + q*4 + j
    //   cols:  n0 + wc*64  + (ni>>1)*32 + (ni&1)*16 + (lane&15)
#pragma unroll
    for (int mi = 0; mi < 8; ++mi) {
#pragma unroll
        for (int ni = 0; ni < 4; ++ni) {
            const int col = n0 + wc * 64 + (ni >> 1) * 32 + (ni & 1) * 16 + (lane & 15);
            const float bc = bias[col];
#pragma unroll
            for (int j = 0; j < 4; ++j) {
                const int row = m0 + wr * 128 + (mi >> 2) * 64 + (mi & 3) * 16 + q * 4 + j;
                float v = acc[mi][ni][j] + bc;
                if (MODE == 1) {
                    // tanh-form GELU via fast exp (max dev vs erf-GELU ~3e-4)
                    float u = 1.5957691216057308f * (v + 0.044715f * v * v * v);
                    float s = 1.0f / (1.0f + __expf(-u));
                    outh[(size_t)row * N + col] = __float2bfloat16(v * s);
                } else {
                    outf[(size_t)row * N + col] =
                        x[(size_t)row * N + col] * g_res[row] + v * g_post[row];
                }
            }
        }
    }
}

// ---------------------------------------------------------------------------
// Workspace layout (~235.2 MB): W1T, W2T, Abuf, Hbuf, Wfold, gres, gpost
// ---------------------------------------------------------------------------
extern "C" void kernel_launch(void* const* d_in, const int* in_sizes, int n_in,
                              void* d_out, int out_size, void* d_ws, size_t ws_size,
                              hipStream_t stream) {
    const float* x          = (const float*)d_in[0];
    const float* phi_pre_w  = (const float*)d_in[1];
    const float* phi_pre_b  = (const float*)d_in[2];
    const float* phi_post_w = (const float*)d_in[3];
    const float* phi_post_b = (const float*)d_in[4];
    const float* phi_res_w  = (const float*)d_in[5];
    const float* phi_res_b  = (const float*)d_in[6];
    const float* alpha_pre  = (const float*)d_in[7];
    const float* alpha_post = (const float*)d_in[8];
    const float* alpha_res  = (const float*)d_in[9];
    const float* b_pre      = (const float*)d_in[10];
    const float* b_post     = (const float*)d_in[11];
    const float* b_res      = (const float*)d_in[12];
    const float* W1         = (const float*)d_in[13];
    const float* b1         = (const float*)d_in[14];
    const float* W2         = (const float*)d_in[15];
    const float* b2         = (const float*)d_in[16];
    float* out = (float*)d_out;

    char* ws = (char*)d_ws;
    __hip_bfloat16* W1T  = (__hip_bfloat16*)ws;                      // [DFF][DIM]
    __hip_bfloat16* W2T  = W1T + (size_t)DFF * DIM;                  // [DIM][DFF]
    __hip_bfloat16* Abuf = W2T + (size_t)DIM * DFF;                  // [NROWS][DIM]
    __hip_bfloat16* Hbuf = Abuf + (size_t)NROWS * DIM;               // [NROWS][DFF]
    float* Wfold = (float*)(Hbuf + (size_t)NROWS * DFF);             // [24][DIM]
    float* gres  = Wfold + NFOLD * DIM;
    float* gpost = gres + NROWS;

    fold_kernel<<<(NFOLD * DIM + 255) / 256, 256, 0, stream>>>(phi_pre_w, phi_post_w,
                                                               phi_res_w, Wfold);
    transpose_to_bf16<<<dim3(DFF / 32, DIM / 32), 256, 0, stream>>>(W1, W1T, DIM, DFF);
    transpose_to_bf16<<<dim3(DIM / 32, DFF / 32), 256, 0, stream>>>(W2, W2T, DFF, DIM);
    gating_kernel<<<NROWS / 8, 512, 0, stream>>>(x, Wfold, phi_pre_b, phi_post_b, phi_res_b,
                                                 alpha_pre, alpha_post, alpha_res,
                                                 b_pre, b_post, b_res, Abuf, gres, gpost);
    // GEMM1: [8192 x 2048] @ W1 -> gelu -> Hbuf [8192 x 8192]; grid 32x32=1024, NB=4
    gemm256<1, 4><<<1024, 512, 0, stream>>>(
        Abuf, W1T, NROWS, DFF, DIM, b1, Hbuf, nullptr, nullptr, nullptr, nullptr);
    // GEMM2: [8192 x 8192] @ W2 -> out [8192 x 2048]; grid 32x8=256, NB=1
    gemm256<2, 1><<<256, 512, 0, stream>>>(
        Hbuf, W2T, NROWS, DIM, DFF, b2, nullptr, out, x, gres, gpost);
}